// Round 4
// baseline (1020.563 us; speedup 1.0000x reference)
//
#include <hip/hip_runtime.h>
#include <stdint.h>

#define INV_T 10.0f
#define SHIFT_ 460.0f
#define MROWS 8192
#define DDIM 1024
#define CHUNK 1024

typedef __attribute__((ext_vector_type(8))) short bf16x8;
typedef __attribute__((ext_vector_type(4))) float f32x4;

__device__ __forceinline__ float bf2f(unsigned short u) {
  return __uint_as_float(((unsigned int)u) << 16);
}
__device__ __forceinline__ unsigned short f2bf(float f) {
  unsigned int u = __float_as_uint(f);
  return (unsigned short)((u + 0x7FFFu + ((u >> 16) & 1u)) >> 16);
}
__device__ __forceinline__ void gl2lds16(const unsigned short* g, unsigned short* l) {
  __builtin_amdgcn_global_load_lds((const __attribute__((address_space(1))) void*)g,
                                   (__attribute__((address_space(3))) void*)l, 16, 0, 0);
}

// ---------------- prep: fp32 -> bf16 cast + row sum-of-squares ----------------
__global__ void prep_kernel(const float* __restrict__ gen, const float* __restrict__ pos,
                            unsigned short* __restrict__ gen_h, unsigned short* __restrict__ pos_h,
                            float* __restrict__ gn2, float* __restrict__ pn2) {
  int b = blockIdx.x;
  const float* src; unsigned short* dst; float* n2; int row;
  if (b < MROWS) { src = gen; dst = gen_h; n2 = gn2; row = b; }
  else           { src = pos; dst = pos_h; n2 = pn2; row = b - MROWS; }
  int t = threadIdx.x;
  float4 v = ((const float4*)(src + (size_t)row * DDIM))[t];
  float ss = v.x * v.x + v.y * v.y + v.z * v.z + v.w * v.w;
  ushort4 o;
  o.x = f2bf(v.x); o.y = f2bf(v.y); o.z = f2bf(v.z); o.w = f2bf(v.w);
  ((ushort4*)(dst + (size_t)row * DDIM))[t] = o;
#pragma unroll
  for (int m = 1; m < 64; m <<= 1) ss += __shfl_xor(ss, m);
  __shared__ float red[4];
  if ((t & 63) == 0) red[t >> 6] = ss;
  __syncthreads();
  if (t == 0) n2[row] = red[0] + red[1] + red[2] + red[3];
}

// ---------------- transpose: fp32 [8192][1024] -> bf16 [1024][8192] ----------------
__global__ void transpose_kernel(const float* __restrict__ gen, const float* __restrict__ pos,
                                 unsigned short* __restrict__ genT, unsigned short* __restrict__ posT) {
  __shared__ float tile[64][65];
  int b = blockIdx.x;
  const float* src; unsigned short* dst;
  if (b < 2048) { src = gen; dst = genT; }
  else          { src = pos; dst = posT; b -= 2048; }
  int tj = b >> 4, td = b & 15;
  int t = threadIdx.x;
#pragma unroll
  for (int it = 0; it < 16; ++it) {
    int idx = it * 256 + t;
    int r = idx >> 6, c = idx & 63;
    tile[r][c] = src[(size_t)(tj * 64 + r) * DDIM + td * 64 + c];
  }
  __syncthreads();
#pragma unroll
  for (int it = 0; it < 16; ++it) {
    int idx = it * 256 + t;
    int d = idx >> 6, j = idx & 63;
    dst[(size_t)(td * 64 + d) * MROWS + tj * 64 + j] = f2bf(tile[j][d]);
  }
}

// ---------------- BT-GEMM: 256x256 tile, 8 waves (2Mx4N), BK=64, 4-phase/K-tile ----------------
// Deep-pipelined schedule (T3+T4 counted vmcnt, T5 setprio, XOR-swizzled LDS carried over).
// Ledger: prologue stages tile0(4 half-tiles)->buf0 + A-lo(1)->buf1, waits vmcnt(2).
// Iter t: P1 reads A-lo+B-lo, stages A-hi(t+1);  P2 reads B-hi, stages B-lo(t+1);
//         P3 reads A-hi, stages B-hi(t+1);       P4 stages A-lo(t+2) into cur, vmcnt(2).
// Each phase: {ds_reads | stage} -> s_barrier -> lgkmcnt(0)+sched_barrier -> setprio(1) 16xMFMA setprio(0) -> s_barrier.
template <int EPI>
__launch_bounds__(512, 2)
__global__ void gemm_bt(const unsigned short* __restrict__ A0, const unsigned short* __restrict__ A1,
                        long lda,
                        const unsigned short* __restrict__ B0, const unsigned short* __restrict__ B1,
                        long ldb, int ksteps,
                        unsigned short* __restrict__ P0, unsigned short* __restrict__ P1,
                        int pld, int j0,
                        const float* __restrict__ qn2,
                        const float* __restrict__ kn2a, const float* __restrict__ kn2b,
                        float* __restrict__ lsum0, float* __restrict__ lsum1,
                        unsigned short* __restrict__ O0, unsigned short* __restrict__ O1,
                        int first) {
  __shared__ __align__(16) unsigned short Asm[2][256 * 64];
  __shared__ __align__(16) unsigned short Bsm[2][256 * 64];
  const int z = blockIdx.z;
  const unsigned short* A = z ? A1 : A0;
  const unsigned short* B = z ? B1 : B0;
  const int t = threadIdx.x;
  const int lane = t & 63, l15 = lane & 15, quad = lane >> 4;
  const int w = t >> 6, wm = w >> 2, wn = w & 3;
  const long m0 = (long)blockIdx.x * 256;
  const long n0 = (long)blockIdx.y * 256;
  const int trow = t >> 3;                        // 0..63
  const int tcol = ((t & 7) ^ (trow & 7)) * 8;    // XOR pre-swizzled global 16B unit
  const int uo = (quad ^ (l15 & 7)) * 8;          // swizzled read unit (elems)

  const unsigned short* const Ag = A + (m0 + trow) * lda + tcol;
  const unsigned short* const Bg = B + (n0 + trow) * ldb + tcol;

  f32x4 acc[8][4];
#pragma unroll
  for (int i = 0; i < 8; ++i)
#pragma unroll
    for (int j = 0; j < 4; ++j) acc[i][j] = (f32x4){0.f, 0.f, 0.f, 0.f};

// stage one 128-row half (2x global_load_lds dwordx4 per thread)
#define ST_A(dst, ko, hf)                                                 \
  do {                                                                    \
    const unsigned short* s_ = Ag + (long)((hf) * 128) * lda + (ko);      \
    unsigned short* d_ = (dst) + (hf) * 8192 + t * 8;                     \
    gl2lds16(s_, d_);                                                     \
    gl2lds16(s_ + 64 * lda, d_ + 4096);                                   \
  } while (0)
#define ST_B(dst, ko, hf)                                                 \
  do {                                                                    \
    const unsigned short* s_ = Bg + (long)((hf) * 128) * ldb + (ko);      \
    unsigned short* d_ = (dst) + (hf) * 8192 + t * 8;                     \
    gl2lds16(s_, d_);                                                     \
    gl2lds16(s_ + 64 * ldb, d_ + 4096);                                   \
  } while (0)

  // ---- prologue: tile0 full -> buf0 ; A-lo(tile1) -> buf1 (10 loads in flight)
  ST_A(Asm[0], 0, 0); ST_A(Asm[0], 0, 1);
  ST_B(Bsm[0], 0, 0); ST_B(Bsm[0], 0, 1);
  ST_A(Asm[1], 64, 0);
  asm volatile("s_waitcnt vmcnt(2)" ::: "memory");   // tile0's 8 loads landed
  __builtin_amdgcn_s_barrier();

  unsigned short* Ac = Asm[0]; unsigned short* An = Asm[1];
  unsigned short* Bc = Bsm[0]; unsigned short* Bn = Bsm[1];
  const int rbA = (wm * 128 + l15) * 64;
  const int rbB = (wn * 64 + l15) * 64;

  bf16x8 aR[4][2], bLo[2][2], bHi[2][2];

  for (int ks = 0; ks < ksteps; ++ks) {
    const long ko1 = (long)(ks + 1) * 64;
    const long ko2 = (long)(ks + 2) * 64;
    const bool s1 = (ks + 1 < ksteps), s2 = (ks + 2 < ksteps);

    // ---- phase 1: read A-lo + B-lo ; stage A-hi(next) ; MFMA (lo,lo)
#pragma unroll
    for (int mi = 0; mi < 4; ++mi)
#pragma unroll
      for (int kk = 0; kk < 2; ++kk)
        aR[mi][kk] = *(const bf16x8*)(Ac + rbA + mi * 1024 + (uo ^ (kk * 32)));
#pragma unroll
    for (int ni = 0; ni < 2; ++ni)
#pragma unroll
      for (int kk = 0; kk < 2; ++kk)
        bLo[ni][kk] = *(const bf16x8*)(Bc + rbB + ni * 1024 + (uo ^ (kk * 32)));
    if (s1) ST_A(An, ko1, 1);
    __builtin_amdgcn_s_barrier();
    asm volatile("s_waitcnt lgkmcnt(0)" ::: "memory");
    __builtin_amdgcn_sched_barrier(0);
    __builtin_amdgcn_s_setprio(1);
#pragma unroll
    for (int mi = 0; mi < 4; ++mi)
#pragma unroll
      for (int ni = 0; ni < 2; ++ni)
#pragma unroll
        for (int kk = 0; kk < 2; ++kk)
          acc[mi][ni] = __builtin_amdgcn_mfma_f32_16x16x32_bf16(aR[mi][kk], bLo[ni][kk], acc[mi][ni], 0, 0, 0);
    __builtin_amdgcn_s_setprio(0);
    __builtin_amdgcn_s_barrier();

    // ---- phase 2: read B-hi ; stage B-lo(next) ; MFMA (lo,hi)
#pragma unroll
    for (int ni = 0; ni < 2; ++ni)
#pragma unroll
      for (int kk = 0; kk < 2; ++kk)
        bHi[ni][kk] = *(const bf16x8*)(Bc + rbB + (ni + 2) * 1024 + (uo ^ (kk * 32)));
    if (s1) ST_B(Bn, ko1, 0);
    __builtin_amdgcn_s_barrier();
    asm volatile("s_waitcnt lgkmcnt(0)" ::: "memory");
    __builtin_amdgcn_sched_barrier(0);
    __builtin_amdgcn_s_setprio(1);
#pragma unroll
    for (int mi = 0; mi < 4; ++mi)
#pragma unroll
      for (int ni = 0; ni < 2; ++ni)
#pragma unroll
        for (int kk = 0; kk < 2; ++kk)
          acc[mi][ni + 2] = __builtin_amdgcn_mfma_f32_16x16x32_bf16(aR[mi][kk], bHi[ni][kk], acc[mi][ni + 2], 0, 0, 0);
    __builtin_amdgcn_s_setprio(0);
    __builtin_amdgcn_s_barrier();

    // ---- phase 3: read A-hi (overwrites aR) ; stage B-hi(next) ; MFMA (hi,hi)
#pragma unroll
    for (int mi = 0; mi < 4; ++mi)
#pragma unroll
      for (int kk = 0; kk < 2; ++kk)
        aR[mi][kk] = *(const bf16x8*)(Ac + rbA + (mi + 4) * 1024 + (uo ^ (kk * 32)));
    if (s1) ST_B(Bn, ko1, 1);
    __builtin_amdgcn_s_barrier();
    asm volatile("s_waitcnt lgkmcnt(0)" ::: "memory");
    __builtin_amdgcn_sched_barrier(0);
    __builtin_amdgcn_s_setprio(1);
#pragma unroll
    for (int mi = 0; mi < 4; ++mi)
#pragma unroll
      for (int ni = 0; ni < 2; ++ni)
#pragma unroll
        for (int kk = 0; kk < 2; ++kk)
          acc[mi + 4][ni + 2] = __builtin_amdgcn_mfma_f32_16x16x32_bf16(aR[mi][kk], bHi[ni][kk], acc[mi + 4][ni + 2], 0, 0, 0);
    __builtin_amdgcn_s_setprio(0);
    __builtin_amdgcn_s_barrier();

    // ---- phase 4: stage A-lo(t+2) into cur (its reads finished in P1) ; counted vmcnt ; MFMA (hi,lo)
    if (s2) {
      ST_A(Ac, ko2, 0);
      asm volatile("s_waitcnt vmcnt(2)" ::: "memory");  // all of tile t+1 landed; A-lo(t+2) may fly
    } else {
      asm volatile("s_waitcnt vmcnt(0)" ::: "memory");
    }
    __builtin_amdgcn_s_barrier();
    __builtin_amdgcn_s_setprio(1);
#pragma unroll
    for (int mi = 0; mi < 4; ++mi)
#pragma unroll
      for (int ni = 0; ni < 2; ++ni)
#pragma unroll
        for (int kk = 0; kk < 2; ++kk)
          acc[mi + 4][ni] = __builtin_amdgcn_mfma_f32_16x16x32_bf16(aR[mi][kk], bLo[ni][kk], acc[mi + 4][ni], 0, 0, 0);
    __builtin_amdgcn_s_setprio(0);
    __builtin_amdgcn_s_barrier();

    unsigned short* tp;
    tp = Ac; Ac = An; An = tp;
    tp = Bc; Bc = Bn; Bn = tp;
  }
#undef ST_A
#undef ST_B

  if (EPI == 0) {
    unsigned short* Pout = z ? P1 : P0;
    const float* kn2 = z ? kn2b : kn2a;
    float* lsum = z ? lsum1 : lsum0;
#pragma unroll
    for (int mi = 0; mi < 8; ++mi) {
      float rs[4] = {0.f, 0.f, 0.f, 0.f};
#pragma unroll
      for (int ni = 0; ni < 4; ++ni) {
        int c = (int)n0 + wn * 64 + ni * 16 + l15;  // chunk-local col
        float kn = kn2[j0 + c];
#pragma unroll
        for (int reg = 0; reg < 4; ++reg) {
          long r = m0 + wm * 128 + mi * 16 + quad * 4 + reg;  // C-layout: row = quad*4+reg
          float v = acc[mi][ni][reg];
          float d2 = qn2[r] + kn - 2.0f * v;
          float p = __expf(SHIFT_ - INV_T * sqrtf(fmaxf(d2, 0.0f)));
          if (z && (int)r == (j0 + c)) p = 0.0f;
          rs[reg] += p;
          Pout[r * (long)pld + c] = f2bf(p);
        }
      }
#pragma unroll
      for (int reg = 0; reg < 4; ++reg) {
        float v = rs[reg];
        v += __shfl_xor(v, 1); v += __shfl_xor(v, 2);
        v += __shfl_xor(v, 4); v += __shfl_xor(v, 8);
        if (l15 == 0) atomicAdd(&lsum[m0 + wm * 128 + mi * 16 + quad * 4 + reg], v);
      }
    }
  } else {
    unsigned short* Oh = z ? O1 : O0;
#pragma unroll
    for (int mi = 0; mi < 8; ++mi)
#pragma unroll
      for (int ni = 0; ni < 4; ++ni) {
        long c = n0 + wn * 64 + ni * 16 + l15;
#pragma unroll
        for (int reg = 0; reg < 4; ++reg) {
          long r = m0 + wm * 128 + mi * 16 + quad * 4 + reg;
          long off = r * DDIM + c;
          float v = acc[mi][ni][reg];
          Oh[off] = f2bf(first ? v : (bf2f(Oh[off]) + v));
        }
      }
  }
}

// ---------------- merged epilogue: all four stats in one pass; 4 atomics/block ----------------
__global__ void epi_kernel(const unsigned short* __restrict__ OA, const unsigned short* __restrict__ OR_,
                           const float* __restrict__ lsumA, const float* __restrict__ lsumR,
                           const float* __restrict__ genf, float* __restrict__ gs) {
  __shared__ float wsL[4], wsD[4], wsA[4], wsR[4];
  const int t = threadIdx.x;
  const int w = t >> 6;
  const int lane = t & 63;
  float accL = 0.f, accD = 0.f, accA = 0.f, accR = 0.f;

  for (int i = 0; i < 8; ++i) {
    const int row = blockIdx.x * 32 + w * 8 + i;
    const float invlA = 1.0f / lsumA[row];
    const float invlR = 1.0f / lsumR[row];
    float ssA = 0.f, ssR = 0.f, ssD = 0.f;
#pragma unroll
    for (int u = 0; u < 4; ++u) {
      const long off = (long)row * DDIM + u * 256 + lane * 4;
      float4 g = *(const float4*)(genf + off);
      ushort4 oa = *(const ushort4*)(OA + off);
      ushort4 orr = *(const ushort4*)(OR_ + off);
      float g4[4] = {g.x, g.y, g.z, g.w};
      float a4[4] = {bf2f(oa.x), bf2f(oa.y), bf2f(oa.z), bf2f(oa.w)};
      float r4[4] = {bf2f(orr.x), bf2f(orr.y), bf2f(orr.z), bf2f(orr.w)};
#pragma unroll
      for (int e = 0; e < 4; ++e) {
        float a_ = a4[e] * invlA - g4[e];
        float r_ = r4[e] * invlR - g4[e];
        float d_ = a_ - r_;
        ssA += a_ * a_; ssR += r_ * r_; ssD += d_ * d_;
      }
    }
#pragma unroll
    for (int m = 1; m < 64; m <<= 1) {
      ssA += __shfl_xor(ssA, m);
      ssR += __shfl_xor(ssR, m);
      ssD += __shfl_xor(ssD, m);
    }
    accA += sqrtf(ssA); accR += sqrtf(ssR); accD += sqrtf(ssD); accL += ssD;
  }
  if (lane == 0) { wsL[w] = accL; wsD[w] = accD; wsA[w] = accA; wsR[w] = accR; }
  __syncthreads();
  if (t == 0) {
    atomicAdd(&gs[0], wsL[0] + wsL[1] + wsL[2] + wsL[3]);
    atomicAdd(&gs[1], wsD[0] + wsD[1] + wsD[2] + wsD[3]);
    atomicAdd(&gs[2], wsA[0] + wsA[1] + wsA[2] + wsA[3]);
    atomicAdd(&gs[3], wsR[0] + wsR[1] + wsR[2] + wsR[3]);
  }
}

__global__ void finalize_kernel(const float* __restrict__ gs, float* __restrict__ out) {
  int t = threadIdx.x;
  if (t == 0) out[0] = gs[0] / (8192.0f * 1024.0f);
  if (t == 1) out[1] = gs[1] / 8192.0f;
  if (t == 2) out[2] = gs[2] / 8192.0f;
  if (t == 3) out[3] = gs[3] / 8192.0f;
}

extern "C" void kernel_launch(void* const* d_in, const int* in_sizes, int n_in,
                              void* d_out, int out_size, void* d_ws, size_t ws_size,
                              hipStream_t stream) {
  const float* gen = (const float*)d_in[0];
  const float* pos = (const float*)d_in[1];
  char* ws = (char*)d_ws;
  const size_t MB = (size_t)1 << 20;
  unsigned short* gen_h = (unsigned short*)(ws + 0 * MB);    // 16 MB
  unsigned short* pos_h = (unsigned short*)(ws + 16 * MB);   // 16 MB
  unsigned short* genT  = (unsigned short*)(ws + 32 * MB);   // 16 MB
  unsigned short* posT  = (unsigned short*)(ws + 48 * MB);   // 16 MB
  unsigned short* Pa    = (unsigned short*)(ws + 64 * MB);   // 16 MB  (attr P chunk)
  unsigned short* Pr    = (unsigned short*)(ws + 80 * MB);   // 16 MB  (rep P chunk)
  unsigned short* OhA   = (unsigned short*)(ws + 96 * MB);   // 16 MB  (attr O, bf16)
  unsigned short* OhR   = (unsigned short*)(ws + 112 * MB);  // 16 MB  (rep O, bf16)
  float* gn2   = (float*)(ws + 128 * MB);                    // 32 KB
  float* pn2   = (float*)(ws + 128 * MB + 32768);            // 32 KB
  float* lsumA = (float*)(ws + 128 * MB + 65536);            // 32 KB
  float* lsumR = (float*)(ws + 128 * MB + 98304);            // 32 KB
  float* gs    = (float*)(ws + 128 * MB + 131072);           // 16 B

  hipMemsetAsync(gs, 0, 4 * sizeof(float), stream);
  hipMemsetAsync(lsumA, 0, 2 * MROWS * sizeof(float), stream);  // lsumA + lsumR contiguous
  prep_kernel<<<dim3(16384), dim3(256), 0, stream>>>(gen, pos, gen_h, pos_h, gn2, pn2);
  transpose_kernel<<<dim3(4096), dim3(256), 0, stream>>>(gen, pos, genT, posT);

  const int nchunks = MROWS / CHUNK;
  for (int c = 0; c < nchunks; ++c) {
    const int j0 = c * CHUNK;
    // PassA: S-chunk for both streams; A = gen_h for both, B = pos_h / gen_h rows [j0, j0+CHUNK)
    gemm_bt<0><<<dim3(MROWS / 256, CHUNK / 256, 2), dim3(512), 0, stream>>>(
        gen_h, gen_h, DDIM,
        pos_h + (long)j0 * DDIM, gen_h + (long)j0 * DDIM, DDIM, DDIM / 64,
        Pa, Pr, CHUNK, j0, gn2, pn2, gn2, lsumA, lsumR, nullptr, nullptr, 0);
    // PassB: O += P-chunk @ V; A = P chunks, B = transposed V slabs
    gemm_bt<1><<<dim3(MROWS / 256, DDIM / 256, 2), dim3(512), 0, stream>>>(
        Pa, Pr, CHUNK,
        posT + j0, genT + j0, MROWS, CHUNK / 64,
        nullptr, nullptr, 0, 0, nullptr, nullptr, nullptr, nullptr, nullptr,
        OhA, OhR, c == 0);
  }

  epi_kernel<<<dim3(256), dim3(256), 0, stream>>>(OhA, OhR, lsumA, lsumR, gen, gs);
  finalize_kernel<<<dim3(1), dim3(64), 0, stream>>>(gs, (float*)d_out);
}

// Round 5
// 984.862 us; speedup vs baseline: 1.0362x; 1.0362x over previous
//
#include <hip/hip_runtime.h>
#include <stdint.h>

#define INV_T 10.0f
#define SHIFT_ 460.0f
#define MROWS 8192
#define DDIM 1024
#define CHUNK 1024

typedef __attribute__((ext_vector_type(8))) short bf16x8;
typedef __attribute__((ext_vector_type(4))) float f32x4;

__device__ __forceinline__ float bf2f(unsigned short u) {
  return __uint_as_float(((unsigned int)u) << 16);
}
__device__ __forceinline__ unsigned short f2bf(float f) {
  unsigned int u = __float_as_uint(f);
  return (unsigned short)((u + 0x7FFFu + ((u >> 16) & 1u)) >> 16);
}
__device__ __forceinline__ void gl2lds16(const unsigned short* g, unsigned short* l) {
  __builtin_amdgcn_global_load_lds((const __attribute__((address_space(1))) void*)g,
                                   (__attribute__((address_space(3))) void*)l, 16, 0, 0);
}

// ---------------- prep: fp32 -> bf16 cast + row sum-of-squares ----------------
__global__ void prep_kernel(const float* __restrict__ gen, const float* __restrict__ pos,
                            unsigned short* __restrict__ gen_h, unsigned short* __restrict__ pos_h,
                            float* __restrict__ gn2, float* __restrict__ pn2) {
  int b = blockIdx.x;
  const float* src; unsigned short* dst; float* n2; int row;
  if (b < MROWS) { src = gen; dst = gen_h; n2 = gn2; row = b; }
  else           { src = pos; dst = pos_h; n2 = pn2; row = b - MROWS; }
  int t = threadIdx.x;
  float4 v = ((const float4*)(src + (size_t)row * DDIM))[t];
  float ss = v.x * v.x + v.y * v.y + v.z * v.z + v.w * v.w;
  ushort4 o;
  o.x = f2bf(v.x); o.y = f2bf(v.y); o.z = f2bf(v.z); o.w = f2bf(v.w);
  ((ushort4*)(dst + (size_t)row * DDIM))[t] = o;
#pragma unroll
  for (int m = 1; m < 64; m <<= 1) ss += __shfl_xor(ss, m);
  __shared__ float red[4];
  if ((t & 63) == 0) red[t >> 6] = ss;
  __syncthreads();
  if (t == 0) n2[row] = red[0] + red[1] + red[2] + red[3];
}

// ---------------- transpose: fp32 [8192][1024] -> bf16 [1024][8192] ----------------
__global__ void transpose_kernel(const float* __restrict__ gen, const float* __restrict__ pos,
                                 unsigned short* __restrict__ genT, unsigned short* __restrict__ posT) {
  __shared__ float tile[64][65];
  int b = blockIdx.x;
  const float* src; unsigned short* dst;
  if (b < 2048) { src = gen; dst = genT; }
  else          { src = pos; dst = posT; b -= 2048; }
  int tj = b >> 4, td = b & 15;
  int t = threadIdx.x;
#pragma unroll
  for (int it = 0; it < 16; ++it) {
    int idx = it * 256 + t;
    int r = idx >> 6, c = idx & 63;
    tile[r][c] = src[(size_t)(tj * 64 + r) * DDIM + td * 64 + c];
  }
  __syncthreads();
#pragma unroll
  for (int it = 0; it < 16; ++it) {
    int idx = it * 256 + t;
    int d = idx >> 6, j = idx & 63;
    dst[(size_t)(td * 64 + d) * MROWS + tj * 64 + j] = f2bf(tile[j][d]);
  }
}

// ---------------- BT-GEMM: 256x256 tile, 8 waves (2Mx4N), BK=64 ----------------
// Double-buffered, counted-vmcnt, TWO barriers per K-tile (minimum sync):
//   body: {read lo frags; stage A-hi/B-lo/B-hi(t+1); MFMA lo-quadrants;
//          read hi frags; MFMA hi-quadrants}
//   lgkmcnt(0); barrier;            // all reads returned -> safe to restage Ac.lo
//   ST_A(Ac, A-lo(t+2)); vmcnt(2);  // drains all of tile t+1, leaves A-lo(t+2) flying
//   barrier;                        // tile t+1 visible to all waves
// Compiler fine-schedules ds_read<->MFMA inside the unbarriered region (m97 finding);
// no per-phase drains, no sched_barrier, no setprio (null without phase-split, m190).
template <int EPI>
__launch_bounds__(512, 2)
__global__ void gemm_bt(const unsigned short* __restrict__ A0, const unsigned short* __restrict__ A1,
                        long lda,
                        const unsigned short* __restrict__ B0, const unsigned short* __restrict__ B1,
                        long ldb, int ksteps,
                        unsigned short* __restrict__ P0, unsigned short* __restrict__ P1,
                        int pld, int j0,
                        const float* __restrict__ qn2,
                        const float* __restrict__ kn2a, const float* __restrict__ kn2b,
                        float* __restrict__ lsum0, float* __restrict__ lsum1,
                        unsigned short* __restrict__ O0, unsigned short* __restrict__ O1,
                        int first) {
  __shared__ __align__(16) unsigned short Asm[2][256 * 64];
  __shared__ __align__(16) unsigned short Bsm[2][256 * 64];
  const int z = blockIdx.z;
  const unsigned short* A = z ? A1 : A0;
  const unsigned short* B = z ? B1 : B0;
  const int t = threadIdx.x;
  const int lane = t & 63, l15 = lane & 15, quad = lane >> 4;
  const int w = t >> 6, wm = w >> 2, wn = w & 3;
  const long m0 = (long)blockIdx.x * 256;
  const long n0 = (long)blockIdx.y * 256;
  const int trow = t >> 3;                        // 0..63
  const int tcol = ((t & 7) ^ (trow & 7)) * 8;    // XOR pre-swizzled global 16B unit
  const int uo = (quad ^ (l15 & 7)) * 8;          // swizzled read unit (elems)

  const unsigned short* const Ag = A + (m0 + trow) * lda + tcol;
  const unsigned short* const Bg = B + (n0 + trow) * ldb + tcol;

  f32x4 acc[8][4];
#pragma unroll
  for (int i = 0; i < 8; ++i)
#pragma unroll
    for (int j = 0; j < 4; ++j) acc[i][j] = (f32x4){0.f, 0.f, 0.f, 0.f};

// stage one 128-row half (2x global_load_lds dwordx4 per thread)
#define ST_A(dst, ko, hf)                                                 \
  do {                                                                    \
    const unsigned short* s_ = Ag + (long)((hf) * 128) * lda + (ko);      \
    unsigned short* d_ = (dst) + (hf) * 8192 + t * 8;                     \
    gl2lds16(s_, d_);                                                     \
    gl2lds16(s_ + 64 * lda, d_ + 4096);                                   \
  } while (0)
#define ST_B(dst, ko, hf)                                                 \
  do {                                                                    \
    const unsigned short* s_ = Bg + (long)((hf) * 128) * ldb + (ko);      \
    unsigned short* d_ = (dst) + (hf) * 8192 + t * 8;                     \
    gl2lds16(s_, d_);                                                     \
    gl2lds16(s_ + 64 * ldb, d_ + 4096);                                   \
  } while (0)

  // ---- prologue: tile0 full -> buf0 ; A-lo(tile1) -> buf1 (10 loads in flight)
  ST_A(Asm[0], 0, 0); ST_A(Asm[0], 0, 1);
  ST_B(Bsm[0], 0, 0); ST_B(Bsm[0], 0, 1);
  ST_A(Asm[1], 64, 0);
  asm volatile("s_waitcnt vmcnt(2)" ::: "memory");   // tile0's 8 loads landed
  __builtin_amdgcn_s_barrier();

  unsigned short* Ac = Asm[0]; unsigned short* An = Asm[1];
  unsigned short* Bc = Bsm[0]; unsigned short* Bn = Bsm[1];
  const int rbA = (wm * 128 + l15) * 64;
  const int rbB = (wn * 64 + l15) * 64;

  bf16x8 aR[4][2], bLo[2][2], bHi[2][2];

  for (int ks = 0; ks < ksteps; ++ks) {
    const long ko1 = (long)(ks + 1) * 64;
    const long ko2 = (long)(ks + 2) * 64;
    const bool s1 = (ks + 1 < ksteps), s2 = (ks + 2 < ksteps);

    // ---- read lo-half fragments: A-lo (8), B-lo (4), B-hi (4)
#pragma unroll
    for (int mi = 0; mi < 4; ++mi)
#pragma unroll
      for (int kk = 0; kk < 2; ++kk)
        aR[mi][kk] = *(const bf16x8*)(Ac + rbA + mi * 1024 + (uo ^ (kk * 32)));
#pragma unroll
    for (int ni = 0; ni < 2; ++ni)
#pragma unroll
      for (int kk = 0; kk < 2; ++kk)
        bLo[ni][kk] = *(const bf16x8*)(Bc + rbB + ni * 1024 + (uo ^ (kk * 32)));
#pragma unroll
    for (int ni = 0; ni < 2; ++ni)
#pragma unroll
      for (int kk = 0; kk < 2; ++kk)
        bHi[ni][kk] = *(const bf16x8*)(Bc + rbB + (ni + 2) * 1024 + (uo ^ (kk * 32)));

    // ---- stage tile t+1 (A-hi, B-lo, B-hi) early: latency hides under MFMAs
    if (s1) {
      ST_A(An, ko1, 1);
      ST_B(Bn, ko1, 0);
      ST_B(Bn, ko1, 1);
    }

    // ---- MFMA lo quadrants: (lo,lo) and (lo,hi)  (32 MFMA)
#pragma unroll
    for (int mi = 0; mi < 4; ++mi)
#pragma unroll
      for (int ni = 0; ni < 2; ++ni)
#pragma unroll
        for (int kk = 0; kk < 2; ++kk) {
          acc[mi][ni] = __builtin_amdgcn_mfma_f32_16x16x32_bf16(aR[mi][kk], bLo[ni][kk], acc[mi][ni], 0, 0, 0);
          acc[mi][ni + 2] = __builtin_amdgcn_mfma_f32_16x16x32_bf16(aR[mi][kk], bHi[ni][kk], acc[mi][ni + 2], 0, 0, 0);
        }

    // ---- read hi-half A fragments (reuse aR regs)
#pragma unroll
    for (int mi = 0; mi < 4; ++mi)
#pragma unroll
      for (int kk = 0; kk < 2; ++kk)
        aR[mi][kk] = *(const bf16x8*)(Ac + rbA + (mi + 4) * 1024 + (uo ^ (kk * 32)));

    // ---- MFMA hi quadrants: (hi,hi) and (hi,lo)  (32 MFMA)
#pragma unroll
    for (int mi = 0; mi < 4; ++mi)
#pragma unroll
      for (int ni = 0; ni < 2; ++ni)
#pragma unroll
        for (int kk = 0; kk < 2; ++kk) {
          acc[mi + 4][ni + 2] = __builtin_amdgcn_mfma_f32_16x16x32_bf16(aR[mi][kk], bHi[ni][kk], acc[mi + 4][ni + 2], 0, 0, 0);
          acc[mi + 4][ni] = __builtin_amdgcn_mfma_f32_16x16x32_bf16(aR[mi][kk], bLo[ni][kk], acc[mi + 4][ni], 0, 0, 0);
        }

    // ---- sync point 1: all this-tile LDS reads returned -> safe to restage Ac.lo
    asm volatile("s_waitcnt lgkmcnt(0)" ::: "memory");
    __builtin_amdgcn_s_barrier();

    // ---- restage A-lo(t+2) into current buffer; counted drain of tile t+1
    if (s2) {
      ST_A(Ac, ko2, 0);
      asm volatile("s_waitcnt vmcnt(2)" ::: "memory");  // tile t+1 landed; A-lo(t+2) may fly
    } else {
      asm volatile("s_waitcnt vmcnt(0)" ::: "memory");
    }
    __builtin_amdgcn_s_barrier();   // tile t+1 visible to all waves

    unsigned short* tp;
    tp = Ac; Ac = An; An = tp;
    tp = Bc; Bc = Bn; Bn = tp;
  }
#undef ST_A
#undef ST_B

  if (EPI == 0) {
    unsigned short* Pout = z ? P1 : P0;
    const float* kn2 = z ? kn2b : kn2a;
    float* lsum = z ? lsum1 : lsum0;
#pragma unroll
    for (int mi = 0; mi < 8; ++mi) {
      float rs[4] = {0.f, 0.f, 0.f, 0.f};
#pragma unroll
      for (int ni = 0; ni < 4; ++ni) {
        int c = (int)n0 + wn * 64 + ni * 16 + l15;  // chunk-local col
        float kn = kn2[j0 + c];
#pragma unroll
        for (int reg = 0; reg < 4; ++reg) {
          long r = m0 + wm * 128 + mi * 16 + quad * 4 + reg;  // C-layout: row = quad*4+reg
          float v = acc[mi][ni][reg];
          float d2 = qn2[r] + kn - 2.0f * v;
          float p = __expf(SHIFT_ - INV_T * sqrtf(fmaxf(d2, 0.0f)));
          if (z && (int)r == (j0 + c)) p = 0.0f;
          rs[reg] += p;
          Pout[r * (long)pld + c] = f2bf(p);
        }
      }
#pragma unroll
      for (int reg = 0; reg < 4; ++reg) {
        float v = rs[reg];
        v += __shfl_xor(v, 1); v += __shfl_xor(v, 2);
        v += __shfl_xor(v, 4); v += __shfl_xor(v, 8);
        if (l15 == 0) atomicAdd(&lsum[m0 + wm * 128 + mi * 16 + quad * 4 + reg], v);
      }
    }
  } else {
    unsigned short* Oh = z ? O1 : O0;
#pragma unroll
    for (int mi = 0; mi < 8; ++mi)
#pragma unroll
      for (int ni = 0; ni < 4; ++ni) {
        long c = n0 + wn * 64 + ni * 16 + l15;
#pragma unroll
        for (int reg = 0; reg < 4; ++reg) {
          long r = m0 + wm * 128 + mi * 16 + quad * 4 + reg;
          long off = r * DDIM + c;
          float v = acc[mi][ni][reg];
          Oh[off] = f2bf(first ? v : (bf2f(Oh[off]) + v));
        }
      }
  }
}

// ---------------- merged epilogue: all four stats in one pass; 4 atomics/block ----------------
__global__ void epi_kernel(const unsigned short* __restrict__ OA, const unsigned short* __restrict__ OR_,
                           const float* __restrict__ lsumA, const float* __restrict__ lsumR,
                           const float* __restrict__ genf, float* __restrict__ gs) {
  __shared__ float wsL[4], wsD[4], wsA[4], wsR[4];
  const int t = threadIdx.x;
  const int w = t >> 6;
  const int lane = t & 63;
  float accL = 0.f, accD = 0.f, accA = 0.f, accR = 0.f;

  for (int i = 0; i < 8; ++i) {
    const int row = blockIdx.x * 32 + w * 8 + i;
    const float invlA = 1.0f / lsumA[row];
    const float invlR = 1.0f / lsumR[row];
    float ssA = 0.f, ssR = 0.f, ssD = 0.f;
#pragma unroll
    for (int u = 0; u < 4; ++u) {
      const long off = (long)row * DDIM + u * 256 + lane * 4;
      float4 g = *(const float4*)(genf + off);
      ushort4 oa = *(const ushort4*)(OA + off);
      ushort4 orr = *(const ushort4*)(OR_ + off);
      float g4[4] = {g.x, g.y, g.z, g.w};
      float a4[4] = {bf2f(oa.x), bf2f(oa.y), bf2f(oa.z), bf2f(oa.w)};
      float r4[4] = {bf2f(orr.x), bf2f(orr.y), bf2f(orr.z), bf2f(orr.w)};
#pragma unroll
      for (int e = 0; e < 4; ++e) {
        float a_ = a4[e] * invlA - g4[e];
        float r_ = r4[e] * invlR - g4[e];
        float d_ = a_ - r_;
        ssA += a_ * a_; ssR += r_ * r_; ssD += d_ * d_;
      }
    }
#pragma unroll
    for (int m = 1; m < 64; m <<= 1) {
      ssA += __shfl_xor(ssA, m);
      ssR += __shfl_xor(ssR, m);
      ssD += __shfl_xor(ssD, m);
    }
    accA += sqrtf(ssA); accR += sqrtf(ssR); accD += sqrtf(ssD); accL += ssD;
  }
  if (lane == 0) { wsL[w] = accL; wsD[w] = accD; wsA[w] = accA; wsR[w] = accR; }
  __syncthreads();
  if (t == 0) {
    atomicAdd(&gs[0], wsL[0] + wsL[1] + wsL[2] + wsL[3]);
    atomicAdd(&gs[1], wsD[0] + wsD[1] + wsD[2] + wsD[3]);
    atomicAdd(&gs[2], wsA[0] + wsA[1] + wsA[2] + wsA[3]);
    atomicAdd(&gs[3], wsR[0] + wsR[1] + wsR[2] + wsR[3]);
  }
}

__global__ void finalize_kernel(const float* __restrict__ gs, float* __restrict__ out) {
  int t = threadIdx.x;
  if (t == 0) out[0] = gs[0] / (8192.0f * 1024.0f);
  if (t == 1) out[1] = gs[1] / 8192.0f;
  if (t == 2) out[2] = gs[2] / 8192.0f;
  if (t == 3) out[3] = gs[3] / 8192.0f;
}

extern "C" void kernel_launch(void* const* d_in, const int* in_sizes, int n_in,
                              void* d_out, int out_size, void* d_ws, size_t ws_size,
                              hipStream_t stream) {
  const float* gen = (const float*)d_in[0];
  const float* pos = (const float*)d_in[1];
  char* ws = (char*)d_ws;
  const size_t MB = (size_t)1 << 20;
  unsigned short* gen_h = (unsigned short*)(ws + 0 * MB);    // 16 MB
  unsigned short* pos_h = (unsigned short*)(ws + 16 * MB);   // 16 MB
  unsigned short* genT  = (unsigned short*)(ws + 32 * MB);   // 16 MB
  unsigned short* posT  = (unsigned short*)(ws + 48 * MB);   // 16 MB
  unsigned short* Pa    = (unsigned short*)(ws + 64 * MB);   // 16 MB  (attr P chunk)
  unsigned short* Pr    = (unsigned short*)(ws + 80 * MB);   // 16 MB  (rep P chunk)
  unsigned short* OhA   = (unsigned short*)(ws + 96 * MB);   // 16 MB  (attr O, bf16)
  unsigned short* OhR   = (unsigned short*)(ws + 112 * MB);  // 16 MB  (rep O, bf16)
  float* gn2   = (float*)(ws + 128 * MB);                    // 32 KB
  float* pn2   = (float*)(ws + 128 * MB + 32768);            // 32 KB
  float* lsumA = (float*)(ws + 128 * MB + 65536);            // 32 KB
  float* lsumR = (float*)(ws + 128 * MB + 98304);            // 32 KB
  float* gs    = (float*)(ws + 128 * MB + 131072);           // 16 B

  hipMemsetAsync(gs, 0, 4 * sizeof(float), stream);
  hipMemsetAsync(lsumA, 0, 2 * MROWS * sizeof(float), stream);  // lsumA + lsumR contiguous
  prep_kernel<<<dim3(16384), dim3(256), 0, stream>>>(gen, pos, gen_h, pos_h, gn2, pn2);
  transpose_kernel<<<dim3(4096), dim3(256), 0, stream>>>(gen, pos, genT, posT);

  const int nchunks = MROWS / CHUNK;
  for (int c = 0; c < nchunks; ++c) {
    const int j0 = c * CHUNK;
    // PassA: S-chunk for both streams; A = gen_h for both, B = pos_h / gen_h rows [j0, j0+CHUNK)
    gemm_bt<0><<<dim3(MROWS / 256, CHUNK / 256, 2), dim3(512), 0, stream>>>(
        gen_h, gen_h, DDIM,
        pos_h + (long)j0 * DDIM, gen_h + (long)j0 * DDIM, DDIM, DDIM / 64,
        Pa, Pr, CHUNK, j0, gn2, pn2, gn2, lsumA, lsumR, nullptr, nullptr, 0);
    // PassB: O += P-chunk @ V; A = P chunks, B = transposed V slabs
    gemm_bt<1><<<dim3(MROWS / 256, DDIM / 256, 2), dim3(512), 0, stream>>>(
        Pa, Pr, CHUNK,
        posT + j0, genT + j0, MROWS, CHUNK / 64,
        nullptr, nullptr, 0, 0, nullptr, nullptr, nullptr, nullptr, nullptr,
        OhA, OhR, c == 0);
  }

  epi_kernel<<<dim3(256), dim3(256), 0, stream>>>(OhA, OhR, lsumA, lsumR, gen, gs);
  finalize_kernel<<<dim3(1), dim3(64), 0, stream>>>(gs, (float*)d_out);
}

// Round 7
// 932.104 us; speedup vs baseline: 1.0949x; 1.0566x over previous
//
#include <hip/hip_runtime.h>
#include <stdint.h>

#define INV_T 10.0f
#define SHIFT_ 460.0f
#define MROWS 8192
#define DDIM 1024
#define CHUNK 1024

typedef __attribute__((ext_vector_type(8))) short bf16x8;
typedef __attribute__((ext_vector_type(4))) float f32x4;

__device__ __forceinline__ float bf2f(unsigned short u) {
  return __uint_as_float(((unsigned int)u) << 16);
}
__device__ __forceinline__ unsigned short f2bf(float f) {
  unsigned int u = __float_as_uint(f);
  return (unsigned short)((u + 0x7FFFu + ((u >> 16) & 1u)) >> 16);
}
__device__ __forceinline__ void gl2lds16(const unsigned short* g, unsigned short* l) {
  __builtin_amdgcn_global_load_lds((const __attribute__((address_space(1))) void*)g,
                                   (__attribute__((address_space(3))) void*)l, 16, 0, 0);
}

// ---------------- prep: fp32 -> bf16 cast + row sum-of-squares ----------------
__global__ void prep_kernel(const float* __restrict__ gen, const float* __restrict__ pos,
                            unsigned short* __restrict__ gen_h, unsigned short* __restrict__ pos_h,
                            float* __restrict__ gn2, float* __restrict__ pn2) {
  int b = blockIdx.x;
  const float* src; unsigned short* dst; float* n2; int row;
  if (b < MROWS) { src = gen; dst = gen_h; n2 = gn2; row = b; }
  else           { src = pos; dst = pos_h; n2 = pn2; row = b - MROWS; }
  int t = threadIdx.x;
  float4 v = ((const float4*)(src + (size_t)row * DDIM))[t];
  float ss = v.x * v.x + v.y * v.y + v.z * v.z + v.w * v.w;
  ushort4 o;
  o.x = f2bf(v.x); o.y = f2bf(v.y); o.z = f2bf(v.z); o.w = f2bf(v.w);
  ((ushort4*)(dst + (size_t)row * DDIM))[t] = o;
#pragma unroll
  for (int m = 1; m < 64; m <<= 1) ss += __shfl_xor(ss, m);
  __shared__ float red[4];
  if ((t & 63) == 0) red[t >> 6] = ss;
  __syncthreads();
  if (t == 0) n2[row] = red[0] + red[1] + red[2] + red[3];
}

// ---------------- transpose: fp32 [8192][1024] -> bf16 [1024][8192] ----------------
__global__ void transpose_kernel(const float* __restrict__ gen, const float* __restrict__ pos,
                                 unsigned short* __restrict__ genT, unsigned short* __restrict__ posT) {
  __shared__ float tile[64][65];
  int b = blockIdx.x;
  const float* src; unsigned short* dst;
  if (b < 2048) { src = gen; dst = genT; }
  else          { src = pos; dst = posT; b -= 2048; }
  int tj = b >> 4, td = b & 15;
  int t = threadIdx.x;
#pragma unroll
  for (int it = 0; it < 16; ++it) {
    int idx = it * 256 + t;
    int r = idx >> 6, c = idx & 63;
    tile[r][c] = src[(size_t)(tj * 64 + r) * DDIM + td * 64 + c];
  }
  __syncthreads();
#pragma unroll
  for (int it = 0; it < 16; ++it) {
    int idx = it * 256 + t;
    int d = idx >> 6, j = idx & 63;
    dst[(size_t)(td * 64 + d) * MROWS + tj * 64 + j] = f2bf(tile[j][d]);
  }
}

// ---------------- BT-GEMM, 128x128 tile, XOR-swizzled LDS, dual-stream via z ----------------
// Round-0 verified structure (54 us/gemm) + ONE change: chunked XCD-aware block swizzle.
// HW assigns orig-id round-robin to XCDs (id%8); remap wid=(orig%8)*(nwg/8)+orig/8 so each
// XCD owns a CONTIGUOUS work chunk, then decompose wid y-fastest: chunk = {bx 0..15} x {by 0..7}
// -> per-XCD L2 working set: A 16 panels (4MB, fits) + B 8 panels (2MB). nwg=1024, %8==0 (bijective).
// EPI 0: score epilogue -> P bf16 chunk + row-sum atomics into lsum
// EPI 1: PV epilogue -> O bf16 (first ? write : accumulate)
template <int EPI>
__launch_bounds__(256, 2)
__global__ void gemm_bt(const unsigned short* __restrict__ A0, const unsigned short* __restrict__ A1,
                        long lda,
                        const unsigned short* __restrict__ B0, const unsigned short* __restrict__ B1,
                        long ldb, int ksteps,
                        unsigned short* __restrict__ P0, unsigned short* __restrict__ P1,
                        int pld, int j0,
                        const float* __restrict__ qn2,
                        const float* __restrict__ kn2a, const float* __restrict__ kn2b,
                        float* __restrict__ lsum0, float* __restrict__ lsum1,
                        unsigned short* __restrict__ O0, unsigned short* __restrict__ O1,
                        int first) {
  __shared__ __align__(16) unsigned short Al[128 * 64];
  __shared__ __align__(16) unsigned short Bl[128 * 64];

  // ---- chunked XCD swizzle (T1), y-fastest decomposition
  const int NXB = gridDim.x, NYB = gridDim.y;                  // 64, 8
  const int nwg = NXB * NYB * gridDim.z;                       // 1024 (%8==0)
  const int orig = blockIdx.x + NXB * (blockIdx.y + NYB * blockIdx.z);
  const int wid = (orig & 7) * (nwg >> 3) + (orig >> 3);
  const int by = wid % NYB;
  const int bx = (wid / NYB) % NXB;
  const int bz = wid / (NYB * NXB);

  const int z = bz;
  const unsigned short* A = z ? A1 : A0;
  const unsigned short* B = z ? B1 : B0;
  const int t = threadIdx.x;
  const int w = t >> 6, lane = t & 63, l15 = lane & 15, quad = lane >> 4;
  const int wm = w >> 1, wn = w & 1;
  const long m0 = (long)bx * 128;
  const long n0 = (long)by * 128;
  const int trow = t >> 3;                       // 0..31
  const int tcol = (((t & 7) ^ (trow & 7)) * 8); // XOR-swizzled global 16B-unit

  f32x4 acc[4][4];
#pragma unroll
  for (int i = 0; i < 4; ++i)
#pragma unroll
    for (int j = 0; j < 4; ++j) acc[i][j] = (f32x4){0.f, 0.f, 0.f, 0.f};

  const unsigned short* Ab = A + (m0 + trow) * lda + tcol;
  const unsigned short* Bb = B + (n0 + trow) * ldb + tcol;
  unsigned short* Alw = Al + t * 8;  // lane-linear LDS dest (byte = t*16)
  unsigned short* Blw = Bl + t * 8;
  const int ue = (quad ^ (l15 & 7)) * 8;  // swizzled read unit (elems)

  for (int ks = 0; ks < ksteps; ++ks) {
    const long ko = (long)ks * 64;
#pragma unroll
    for (int i = 0; i < 4; ++i) gl2lds16(Ab + (long)i * 32 * lda + ko, Alw + i * 2048);
#pragma unroll
    for (int i = 0; i < 4; ++i) gl2lds16(Bb + (long)i * 32 * ldb + ko, Blw + i * 2048);
    __syncthreads();
#pragma unroll
    for (int kk = 0; kk < 2; ++kk) {
      const int uo = ue ^ (kk * 32);
      bf16x8 af[4], bfr[4];
#pragma unroll
      for (int mi = 0; mi < 4; ++mi)
        af[mi] = *(const bf16x8*)(Al + (wm * 64 + mi * 16 + l15) * 64 + uo);
#pragma unroll
      for (int ni = 0; ni < 4; ++ni)
        bfr[ni] = *(const bf16x8*)(Bl + (wn * 64 + ni * 16 + l15) * 64 + uo);
#pragma unroll
      for (int mi = 0; mi < 4; ++mi)
#pragma unroll
        for (int ni = 0; ni < 4; ++ni)
          acc[mi][ni] = __builtin_amdgcn_mfma_f32_16x16x32_bf16(af[mi], bfr[ni], acc[mi][ni], 0, 0, 0);
    }
    __syncthreads();
  }

  if (EPI == 0) {
    unsigned short* Pout = z ? P1 : P0;
    const float* kn2 = z ? kn2b : kn2a;
    float* lsum = z ? lsum1 : lsum0;
#pragma unroll
    for (int mi = 0; mi < 4; ++mi) {
      float rs[4] = {0.f, 0.f, 0.f, 0.f};
#pragma unroll
      for (int ni = 0; ni < 4; ++ni) {
        int c = (int)n0 + wn * 64 + ni * 16 + l15;  // chunk-local col
        float kn = kn2[j0 + c];
#pragma unroll
        for (int reg = 0; reg < 4; ++reg) {
          long r = m0 + wm * 64 + mi * 16 + quad * 4 + reg;  // C-layout: row = quad*4+reg
          float v = acc[mi][ni][reg];
          float d2 = qn2[r] + kn - 2.0f * v;
          float p = __expf(SHIFT_ - INV_T * sqrtf(fmaxf(d2, 0.0f)));
          if (z && (int)r == (j0 + c)) p = 0.0f;
          rs[reg] += p;
          Pout[r * (long)pld + c] = f2bf(p);
        }
      }
#pragma unroll
      for (int reg = 0; reg < 4; ++reg) {
        float v = rs[reg];
        v += __shfl_xor(v, 1); v += __shfl_xor(v, 2);
        v += __shfl_xor(v, 4); v += __shfl_xor(v, 8);
        if (l15 == 0) atomicAdd(&lsum[m0 + wm * 64 + mi * 16 + quad * 4 + reg], v);
      }
    }
  } else {
    unsigned short* Oh = z ? O1 : O0;
#pragma unroll
    for (int mi = 0; mi < 4; ++mi)
#pragma unroll
      for (int ni = 0; ni < 4; ++ni) {
        long c = n0 + wn * 64 + ni * 16 + l15;
#pragma unroll
        for (int reg = 0; reg < 4; ++reg) {
          long r = m0 + wm * 64 + mi * 16 + quad * 4 + reg;
          long off = r * DDIM + c;
          float v = acc[mi][ni][reg];
          Oh[off] = f2bf(first ? v : (bf2f(Oh[off]) + v));
        }
      }
  }
}

// ---------------- merged epilogue: all four stats in one pass; 4 atomics/block ----------------
__global__ void epi_kernel(const unsigned short* __restrict__ OA, const unsigned short* __restrict__ OR_,
                           const float* __restrict__ lsumA, const float* __restrict__ lsumR,
                           const float* __restrict__ genf, float* __restrict__ gs) {
  __shared__ float wsL[4], wsD[4], wsA[4], wsR[4];
  const int t = threadIdx.x;
  const int w = t >> 6;
  const int lane = t & 63;
  float accL = 0.f, accD = 0.f, accA = 0.f, accR = 0.f;

  for (int i = 0; i < 8; ++i) {
    const int row = blockIdx.x * 32 + w * 8 + i;
    const float invlA = 1.0f / lsumA[row];
    const float invlR = 1.0f / lsumR[row];
    float ssA = 0.f, ssR = 0.f, ssD = 0.f;
#pragma unroll
    for (int u = 0; u < 4; ++u) {
      const long off = (long)row * DDIM + u * 256 + lane * 4;
      float4 g = *(const float4*)(genf + off);
      ushort4 oa = *(const ushort4*)(OA + off);
      ushort4 orr = *(const ushort4*)(OR_ + off);
      float g4[4] = {g.x, g.y, g.z, g.w};
      float a4[4] = {bf2f(oa.x), bf2f(oa.y), bf2f(oa.z), bf2f(oa.w)};
      float r4[4] = {bf2f(orr.x), bf2f(orr.y), bf2f(orr.z), bf2f(orr.w)};
#pragma unroll
      for (int e = 0; e < 4; ++e) {
        float a_ = a4[e] * invlA - g4[e];
        float r_ = r4[e] * invlR - g4[e];
        float d_ = a_ - r_;
        ssA += a_ * a_; ssR += r_ * r_; ssD += d_ * d_;
      }
    }
#pragma unroll
    for (int m = 1; m < 64; m <<= 1) {
      ssA += __shfl_xor(ssA, m);
      ssR += __shfl_xor(ssR, m);
      ssD += __shfl_xor(ssD, m);
    }
    accA += sqrtf(ssA); accR += sqrtf(ssR); accD += sqrtf(ssD); accL += ssD;
  }
  if (lane == 0) { wsL[w] = accL; wsD[w] = accD; wsA[w] = accA; wsR[w] = accR; }
  __syncthreads();
  if (t == 0) {
    atomicAdd(&gs[0], wsL[0] + wsL[1] + wsL[2] + wsL[3]);
    atomicAdd(&gs[1], wsD[0] + wsD[1] + wsD[2] + wsD[3]);
    atomicAdd(&gs[2], wsA[0] + wsA[1] + wsA[2] + wsA[3]);
    atomicAdd(&gs[3], wsR[0] + wsR[1] + wsR[2] + wsR[3]);
  }
}

__global__ void finalize_kernel(const float* __restrict__ gs, float* __restrict__ out) {
  int t = threadIdx.x;
  if (t == 0) out[0] = gs[0] / (8192.0f * 1024.0f);
  if (t == 1) out[1] = gs[1] / 8192.0f;
  if (t == 2) out[2] = gs[2] / 8192.0f;
  if (t == 3) out[3] = gs[3] / 8192.0f;
}

extern "C" void kernel_launch(void* const* d_in, const int* in_sizes, int n_in,
                              void* d_out, int out_size, void* d_ws, size_t ws_size,
                              hipStream_t stream) {
  const float* gen = (const float*)d_in[0];
  const float* pos = (const float*)d_in[1];
  char* ws = (char*)d_ws;
  const size_t MB = (size_t)1 << 20;
  unsigned short* gen_h = (unsigned short*)(ws + 0 * MB);    // 16 MB
  unsigned short* pos_h = (unsigned short*)(ws + 16 * MB);   // 16 MB
  unsigned short* genT  = (unsigned short*)(ws + 32 * MB);   // 16 MB
  unsigned short* posT  = (unsigned short*)(ws + 48 * MB);   // 16 MB
  unsigned short* Pa    = (unsigned short*)(ws + 64 * MB);   // 16 MB  (attr P chunk)
  unsigned short* Pr    = (unsigned short*)(ws + 80 * MB);   // 16 MB  (rep P chunk)
  unsigned short* OhA   = (unsigned short*)(ws + 96 * MB);   // 16 MB  (attr O, bf16)
  unsigned short* OhR   = (unsigned short*)(ws + 112 * MB);  // 16 MB  (rep O, bf16)
  float* gn2   = (float*)(ws + 128 * MB);                    // 32 KB
  float* pn2   = (float*)(ws + 128 * MB + 32768);            // 32 KB
  float* lsumA = (float*)(ws + 128 * MB + 65536);            // 32 KB
  float* lsumR = (float*)(ws + 128 * MB + 98304);            // 32 KB
  float* gs    = (float*)(ws + 128 * MB + 131072);           // 16 B

  hipMemsetAsync(gs, 0, 4 * sizeof(float), stream);
  hipMemsetAsync(lsumA, 0, 2 * MROWS * sizeof(float), stream);  // lsumA + lsumR contiguous
  prep_kernel<<<dim3(16384), dim3(256), 0, stream>>>(gen, pos, gen_h, pos_h, gn2, pn2);
  transpose_kernel<<<dim3(4096), dim3(256), 0, stream>>>(gen, pos, genT, posT);

  const int nchunks = MROWS / CHUNK;
  for (int c = 0; c < nchunks; ++c) {
    const int j0 = c * CHUNK;
    // PassA: S-chunk for both streams; A = gen_h for both, B = pos_h / gen_h rows [j0, j0+CHUNK)
    gemm_bt<0><<<dim3(64, CHUNK / 128, 2), dim3(256), 0, stream>>>(
        gen_h, gen_h, DDIM,
        pos_h + (long)j0 * DDIM, gen_h + (long)j0 * DDIM, DDIM, DDIM / 64,
        Pa, Pr, CHUNK, j0, gn2, pn2, gn2, lsumA, lsumR, nullptr, nullptr, 0);
    // PassB: O += P-chunk @ V; A = P chunks, B = transposed V slabs
    gemm_bt<1><<<dim3(64, DDIM / 128, 2), dim3(256), 0, stream>>>(
        Pa, Pr, CHUNK,
        posT + j0, genT + j0, MROWS, CHUNK / 64,
        nullptr, nullptr, 0, 0, nullptr, nullptr, nullptr, nullptr, nullptr,
        OhA, OhR, c == 0);
  }

  epi_kernel<<<dim3(256), dim3(256), 0, stream>>>(OhA, OhR, lsumA, lsumR, gen, gs);
  finalize_kernel<<<dim3(1), dim3(64), 0, stream>>>(gs, (float*)d_out);
}

// Round 8
// 909.687 us; speedup vs baseline: 1.1219x; 1.0246x over previous
//
#include <hip/hip_runtime.h>
#include <stdint.h>

#define INV_T 10.0f
#define SHIFT_ 460.0f
#define MROWS 8192
#define DDIM 1024
#define CHUNK 1024

typedef __attribute__((ext_vector_type(8))) short bf16x8;
typedef __attribute__((ext_vector_type(4))) float f32x4;

__device__ __forceinline__ float bf2f(unsigned short u) {
  return __uint_as_float(((unsigned int)u) << 16);
}
__device__ __forceinline__ unsigned short f2bf(float f) {
  unsigned int u = __float_as_uint(f);
  return (unsigned short)((u + 0x7FFFu + ((u >> 16) & 1u)) >> 16);
}
__device__ __forceinline__ void gl2lds16(const unsigned short* g, unsigned short* l) {
  __builtin_amdgcn_global_load_lds((const __attribute__((address_space(1))) void*)g,
                                   (__attribute__((address_space(3))) void*)l, 16, 0, 0);
}

// ---------------- prep: fp32 -> bf16 cast + row sum-of-squares ----------------
__global__ void prep_kernel(const float* __restrict__ gen, const float* __restrict__ pos,
                            unsigned short* __restrict__ gen_h, unsigned short* __restrict__ pos_h,
                            float* __restrict__ gn2, float* __restrict__ pn2) {
  int b = blockIdx.x;
  const float* src; unsigned short* dst; float* n2; int row;
  if (b < MROWS) { src = gen; dst = gen_h; n2 = gn2; row = b; }
  else           { src = pos; dst = pos_h; n2 = pn2; row = b - MROWS; }
  int t = threadIdx.x;
  float4 v = ((const float4*)(src + (size_t)row * DDIM))[t];
  float ss = v.x * v.x + v.y * v.y + v.z * v.z + v.w * v.w;
  ushort4 o;
  o.x = f2bf(v.x); o.y = f2bf(v.y); o.z = f2bf(v.z); o.w = f2bf(v.w);
  ((ushort4*)(dst + (size_t)row * DDIM))[t] = o;
#pragma unroll
  for (int m = 1; m < 64; m <<= 1) ss += __shfl_xor(ss, m);
  __shared__ float red[4];
  if ((t & 63) == 0) red[t >> 6] = ss;
  __syncthreads();
  if (t == 0) n2[row] = red[0] + red[1] + red[2] + red[3];
}

// ---------------- transpose: fp32 [8192][1024] -> bf16 [1024][8192] ----------------
__global__ void transpose_kernel(const float* __restrict__ gen, const float* __restrict__ pos,
                                 unsigned short* __restrict__ genT, unsigned short* __restrict__ posT) {
  __shared__ float tile[64][65];
  int b = blockIdx.x;
  const float* src; unsigned short* dst;
  if (b < 2048) { src = gen; dst = genT; }
  else          { src = pos; dst = posT; b -= 2048; }
  int tj = b >> 4, td = b & 15;
  int t = threadIdx.x;
#pragma unroll
  for (int it = 0; it < 16; ++it) {
    int idx = it * 256 + t;
    int r = idx >> 6, c = idx & 63;
    tile[r][c] = src[(size_t)(tj * 64 + r) * DDIM + td * 64 + c];
  }
  __syncthreads();
#pragma unroll
  for (int it = 0; it < 16; ++it) {
    int idx = it * 256 + t;
    int d = idx >> 6, j = idx & 63;
    dst[(size_t)(td * 64 + d) * MROWS + tj * 64 + j] = f2bf(tile[j][d]);
  }
}

// ---------------- BT-GEMM, 128x128 tile, XOR-swizzled LDS, dual-stream via z ----------------
// Round-7 verified inner loop, unchanged. Two block->work decompositions:
//   gridDim.y==64 (fused full-P PassA): 8x8 SUPERTILE decomposition -- each XCD's
//     contiguous wid-chunk = 16 supertiles of (8bx x 8by); footprint A 2MB + B 2MB = 4MB = L2.
//   else (chunked PassA / PassB): y-fastest chunked XCD swizzle (round-7).
// EPI 0: score epilogue -> P bf16 + row-sum atomics into lsum
// EPI 1: PV epilogue -> O bf16 (first ? write : accumulate); ksteps may span full K (reg accum)
template <int EPI>
__launch_bounds__(256, 2)
__global__ void gemm_bt(const unsigned short* __restrict__ A0, const unsigned short* __restrict__ A1,
                        long lda,
                        const unsigned short* __restrict__ B0, const unsigned short* __restrict__ B1,
                        long ldb, int ksteps,
                        unsigned short* __restrict__ P0, unsigned short* __restrict__ P1,
                        int pld, int j0,
                        const float* __restrict__ qn2,
                        const float* __restrict__ kn2a, const float* __restrict__ kn2b,
                        float* __restrict__ lsum0, float* __restrict__ lsum1,
                        unsigned short* __restrict__ O0, unsigned short* __restrict__ O1,
                        int first) {
  __shared__ __align__(16) unsigned short Al[128 * 64];
  __shared__ __align__(16) unsigned short Bl[128 * 64];

  const int NXB = gridDim.x, NYB = gridDim.y;
  const int nwg = NXB * NYB * gridDim.z;                       // %8==0 in all launches
  const int orig = blockIdx.x + NXB * (blockIdx.y + NYB * blockIdx.z);
  const int wid = (orig & 7) * (nwg >> 3) + (orig >> 3);
  int bx, by, bz;
  if (NYB == 64) {
    // fused PassA: supertile decomposition (64x64 tile grid, z outermost)
    bz = wid >> 12;                 // 4096 tiles per z
    const int r2 = wid & 4095;
    const int st = r2 >> 6, i = r2 & 63;
    bx = (st & 7) * 8 + (i & 7);
    by = (st >> 3) * 8 + (i >> 3);
  } else {
    by = wid % NYB;
    bx = (wid / NYB) % NXB;
    bz = wid / (NYB * NXB);
  }

  const int z = bz;
  const unsigned short* A = z ? A1 : A0;
  const unsigned short* B = z ? B1 : B0;
  const int t = threadIdx.x;
  const int w = t >> 6, lane = t & 63, l15 = lane & 15, quad = lane >> 4;
  const int wm = w >> 1, wn = w & 1;
  const long m0 = (long)bx * 128;
  const long n0 = (long)by * 128;
  const int trow = t >> 3;                       // 0..31
  const int tcol = (((t & 7) ^ (trow & 7)) * 8); // XOR-swizzled global 16B-unit

  f32x4 acc[4][4];
#pragma unroll
  for (int i = 0; i < 4; ++i)
#pragma unroll
    for (int j = 0; j < 4; ++j) acc[i][j] = (f32x4){0.f, 0.f, 0.f, 0.f};

  const unsigned short* Ab = A + (m0 + trow) * lda + tcol;
  const unsigned short* Bb = B + (n0 + trow) * ldb + tcol;
  unsigned short* Alw = Al + t * 8;  // lane-linear LDS dest (byte = t*16)
  unsigned short* Blw = Bl + t * 8;
  const int ue = (quad ^ (l15 & 7)) * 8;  // swizzled read unit (elems)

  for (int ks = 0; ks < ksteps; ++ks) {
    const long ko = (long)ks * 64;
#pragma unroll
    for (int i = 0; i < 4; ++i) gl2lds16(Ab + (long)i * 32 * lda + ko, Alw + i * 2048);
#pragma unroll
    for (int i = 0; i < 4; ++i) gl2lds16(Bb + (long)i * 32 * ldb + ko, Blw + i * 2048);
    __syncthreads();
#pragma unroll
    for (int kk = 0; kk < 2; ++kk) {
      const int uo = ue ^ (kk * 32);
      bf16x8 af[4], bfr[4];
#pragma unroll
      for (int mi = 0; mi < 4; ++mi)
        af[mi] = *(const bf16x8*)(Al + (wm * 64 + mi * 16 + l15) * 64 + uo);
#pragma unroll
      for (int ni = 0; ni < 4; ++ni)
        bfr[ni] = *(const bf16x8*)(Bl + (wn * 64 + ni * 16 + l15) * 64 + uo);
#pragma unroll
      for (int mi = 0; mi < 4; ++mi)
#pragma unroll
        for (int ni = 0; ni < 4; ++ni)
          acc[mi][ni] = __builtin_amdgcn_mfma_f32_16x16x32_bf16(af[mi], bfr[ni], acc[mi][ni], 0, 0, 0);
    }
    __syncthreads();
  }

  if (EPI == 0) {
    unsigned short* Pout = z ? P1 : P0;
    const float* kn2 = z ? kn2b : kn2a;
    float* lsum = z ? lsum1 : lsum0;
#pragma unroll
    for (int mi = 0; mi < 4; ++mi) {
      float rs[4] = {0.f, 0.f, 0.f, 0.f};
#pragma unroll
      for (int ni = 0; ni < 4; ++ni) {
        int c = (int)n0 + wn * 64 + ni * 16 + l15;  // chunk-local col
        float kn = kn2[j0 + c];
#pragma unroll
        for (int reg = 0; reg < 4; ++reg) {
          long r = m0 + wm * 64 + mi * 16 + quad * 4 + reg;  // C-layout: row = quad*4+reg
          float v = acc[mi][ni][reg];
          float d2 = qn2[r] + kn - 2.0f * v;
          float p = __expf(SHIFT_ - INV_T * sqrtf(fmaxf(d2, 0.0f)));
          if (z && (int)r == (j0 + c)) p = 0.0f;
          rs[reg] += p;
          Pout[r * (long)pld + c] = f2bf(p);
        }
      }
#pragma unroll
      for (int reg = 0; reg < 4; ++reg) {
        float v = rs[reg];
        v += __shfl_xor(v, 1); v += __shfl_xor(v, 2);
        v += __shfl_xor(v, 4); v += __shfl_xor(v, 8);
        if (l15 == 0) atomicAdd(&lsum[m0 + wm * 64 + mi * 16 + quad * 4 + reg], v);
      }
    }
  } else {
    unsigned short* Oh = z ? O1 : O0;
#pragma unroll
    for (int mi = 0; mi < 4; ++mi)
#pragma unroll
      for (int ni = 0; ni < 4; ++ni) {
        long c = n0 + wn * 64 + ni * 16 + l15;
#pragma unroll
        for (int reg = 0; reg < 4; ++reg) {
          long r = m0 + wm * 64 + mi * 16 + quad * 4 + reg;
          long off = r * DDIM + c;
          float v = acc[mi][ni][reg];
          Oh[off] = f2bf(first ? v : (bf2f(Oh[off]) + v));
        }
      }
  }
}

// ---------------- merged epilogue: all four stats in one pass; 4 atomics/block ----------------
__global__ void epi_kernel(const unsigned short* __restrict__ OA, const unsigned short* __restrict__ OR_,
                           const float* __restrict__ lsumA, const float* __restrict__ lsumR,
                           const float* __restrict__ genf, float* __restrict__ gs) {
  __shared__ float wsL[4], wsD[4], wsA[4], wsR[4];
  const int t = threadIdx.x;
  const int w = t >> 6;
  const int lane = t & 63;
  float accL = 0.f, accD = 0.f, accA = 0.f, accR = 0.f;

  for (int i = 0; i < 8; ++i) {
    const int row = blockIdx.x * 32 + w * 8 + i;
    const float invlA = 1.0f / lsumA[row];
    const float invlR = 1.0f / lsumR[row];
    float ssA = 0.f, ssR = 0.f, ssD = 0.f;
#pragma unroll
    for (int u = 0; u < 4; ++u) {
      const long off = (long)row * DDIM + u * 256 + lane * 4;
      float4 g = *(const float4*)(genf + off);
      ushort4 oa = *(const ushort4*)(OA + off);
      ushort4 orr = *(const ushort4*)(OR_ + off);
      float g4[4] = {g.x, g.y, g.z, g.w};
      float a4[4] = {bf2f(oa.x), bf2f(oa.y), bf2f(oa.z), bf2f(oa.w)};
      float r4[4] = {bf2f(orr.x), bf2f(orr.y), bf2f(orr.z), bf2f(orr.w)};
#pragma unroll
      for (int e = 0; e < 4; ++e) {
        float a_ = a4[e] * invlA - g4[e];
        float r_ = r4[e] * invlR - g4[e];
        float d_ = a_ - r_;
        ssA += a_ * a_; ssR += r_ * r_; ssD += d_ * d_;
      }
    }
#pragma unroll
    for (int m = 1; m < 64; m <<= 1) {
      ssA += __shfl_xor(ssA, m);
      ssR += __shfl_xor(ssR, m);
      ssD += __shfl_xor(ssD, m);
    }
    accA += sqrtf(ssA); accR += sqrtf(ssR); accD += sqrtf(ssD); accL += ssD;
  }
  if (lane == 0) { wsL[w] = accL; wsD[w] = accD; wsA[w] = accA; wsR[w] = accR; }
  __syncthreads();
  if (t == 0) {
    atomicAdd(&gs[0], wsL[0] + wsL[1] + wsL[2] + wsL[3]);
    atomicAdd(&gs[1], wsD[0] + wsD[1] + wsD[2] + wsD[3]);
    atomicAdd(&gs[2], wsA[0] + wsA[1] + wsA[2] + wsA[3]);
    atomicAdd(&gs[3], wsR[0] + wsR[1] + wsR[2] + wsR[3]);
  }
}

__global__ void finalize_kernel(const float* __restrict__ gs, float* __restrict__ out) {
  int t = threadIdx.x;
  if (t == 0) out[0] = gs[0] / (8192.0f * 1024.0f);
  if (t == 1) out[1] = gs[1] / 8192.0f;
  if (t == 2) out[2] = gs[2] / 8192.0f;
  if (t == 3) out[3] = gs[3] / 8192.0f;
}

extern "C" void kernel_launch(void* const* d_in, const int* in_sizes, int n_in,
                              void* d_out, int out_size, void* d_ws, size_t ws_size,
                              hipStream_t stream) {
  const float* gen = (const float*)d_in[0];
  const float* pos = (const float*)d_in[1];
  char* ws = (char*)d_ws;
  const size_t MB = (size_t)1 << 20;
  const size_t need_fused = 352 * MB + 4 * 32768 + 64;

  if (ws_size >= need_fused) {
    // ---------------- fused path: full-P materialization, 2 deep gemm dispatches ----------------
    unsigned short* gen_h = (unsigned short*)(ws + 0 * MB);    // 16 MB
    unsigned short* pos_h = (unsigned short*)(ws + 16 * MB);   // 16 MB
    unsigned short* genT  = (unsigned short*)(ws + 32 * MB);   // 16 MB
    unsigned short* posT  = (unsigned short*)(ws + 48 * MB);   // 16 MB
    unsigned short* Pa    = (unsigned short*)(ws + 64 * MB);   // 128 MB (full attr P)
    unsigned short* Pr    = (unsigned short*)(ws + 192 * MB);  // 128 MB (full rep P)
    unsigned short* OhA   = (unsigned short*)(ws + 320 * MB);  // 16 MB
    unsigned short* OhR   = (unsigned short*)(ws + 336 * MB);  // 16 MB
    float* gn2   = (float*)(ws + 352 * MB);
    float* pn2   = (float*)(ws + 352 * MB + 32768);
    float* lsumA = (float*)(ws + 352 * MB + 65536);
    float* lsumR = (float*)(ws + 352 * MB + 98304);
    float* gs    = (float*)(ws + 352 * MB + 131072);

    hipMemsetAsync(gs, 0, 4 * sizeof(float), stream);
    hipMemsetAsync(lsumA, 0, 2 * MROWS * sizeof(float), stream);
    prep_kernel<<<dim3(16384), dim3(256), 0, stream>>>(gen, pos, gen_h, pos_h, gn2, pn2);
    transpose_kernel<<<dim3(4096), dim3(256), 0, stream>>>(gen, pos, genT, posT);

    // PassA: full S for both streams in ONE dispatch (supertile XCD decomposition)
    gemm_bt<0><<<dim3(64, 64, 2), dim3(256), 0, stream>>>(
        gen_h, gen_h, DDIM,
        pos_h, gen_h, DDIM, DDIM / 64,
        Pa, Pr, MROWS /*pld*/, 0 /*j0*/, gn2, pn2, gn2, lsumA, lsumR, nullptr, nullptr, 0);
    // PassB: O = P @ V over FULL K=8192 in registers -> single O write, no RMW
    gemm_bt<1><<<dim3(64, DDIM / 128, 2), dim3(256), 0, stream>>>(
        Pa, Pr, MROWS,
        posT, genT, MROWS, MROWS / 64,
        nullptr, nullptr, 0, 0, nullptr, nullptr, nullptr, nullptr, nullptr,
        OhA, OhR, 1);

    epi_kernel<<<dim3(256), dim3(256), 0, stream>>>(OhA, OhR, lsumA, lsumR, gen, gs);
    finalize_kernel<<<dim3(1), dim3(64), 0, stream>>>(gs, (float*)d_out);
  } else {
    // ---------------- fallback: round-7 chunked path (verified) ----------------
    unsigned short* gen_h = (unsigned short*)(ws + 0 * MB);    // 16 MB
    unsigned short* pos_h = (unsigned short*)(ws + 16 * MB);   // 16 MB
    unsigned short* genT  = (unsigned short*)(ws + 32 * MB);   // 16 MB
    unsigned short* posT  = (unsigned short*)(ws + 48 * MB);   // 16 MB
    unsigned short* Pa    = (unsigned short*)(ws + 64 * MB);   // 16 MB  (attr P chunk)
    unsigned short* Pr    = (unsigned short*)(ws + 80 * MB);   // 16 MB  (rep P chunk)
    unsigned short* OhA   = (unsigned short*)(ws + 96 * MB);   // 16 MB  (attr O, bf16)
    unsigned short* OhR   = (unsigned short*)(ws + 112 * MB);  // 16 MB  (rep O, bf16)
    float* gn2   = (float*)(ws + 128 * MB);
    float* pn2   = (float*)(ws + 128 * MB + 32768);
    float* lsumA = (float*)(ws + 128 * MB + 65536);
    float* lsumR = (float*)(ws + 128 * MB + 98304);
    float* gs    = (float*)(ws + 128 * MB + 131072);

    hipMemsetAsync(gs, 0, 4 * sizeof(float), stream);
    hipMemsetAsync(lsumA, 0, 2 * MROWS * sizeof(float), stream);
    prep_kernel<<<dim3(16384), dim3(256), 0, stream>>>(gen, pos, gen_h, pos_h, gn2, pn2);
    transpose_kernel<<<dim3(4096), dim3(256), 0, stream>>>(gen, pos, genT, posT);

    const int nchunks = MROWS / CHUNK;
    for (int c = 0; c < nchunks; ++c) {
      const int j0 = c * CHUNK;
      gemm_bt<0><<<dim3(64, CHUNK / 128, 2), dim3(256), 0, stream>>>(
          gen_h, gen_h, DDIM,
          pos_h + (long)j0 * DDIM, gen_h + (long)j0 * DDIM, DDIM, DDIM / 64,
          Pa, Pr, CHUNK, j0, gn2, pn2, gn2, lsumA, lsumR, nullptr, nullptr, 0);
      gemm_bt<1><<<dim3(64, DDIM / 128, 2), dim3(256), 0, stream>>>(
          Pa, Pr, CHUNK,
          posT + j0, genT + j0, MROWS, CHUNK / 64,
          nullptr, nullptr, 0, 0, nullptr, nullptr, nullptr, nullptr, nullptr,
          OhA, OhR, c == 0);
    }

    epi_kernel<<<dim3(256), dim3(256), 0, stream>>>(OhA, OhR, lsumA, lsumR, gen, gs);
    finalize_kernel<<<dim3(1), dim3(64), 0, stream>>>(gs, (float*)d_out);
  }
}

// Round 9
// 895.016 us; speedup vs baseline: 1.1403x; 1.0164x over previous
//
#include <hip/hip_runtime.h>
#include <stdint.h>

#define INV_T 10.0f
#define SHIFT_ 460.0f
#define MROWS 8192
#define DDIM 1024
#define CHUNK 1024

typedef __attribute__((ext_vector_type(8))) short bf16x8;
typedef __attribute__((ext_vector_type(4))) float f32x4;

__device__ __forceinline__ float bf2f(unsigned short u) {
  return __uint_as_float(((unsigned int)u) << 16);
}
__device__ __forceinline__ unsigned short f2bf(float f) {
  unsigned int u = __float_as_uint(f);
  return (unsigned short)((u + 0x7FFFu + ((u >> 16) & 1u)) >> 16);
}
__device__ __forceinline__ void gl2lds16(const unsigned short* g, unsigned short* l) {
  __builtin_amdgcn_global_load_lds((const __attribute__((address_space(1))) void*)g,
                                   (__attribute__((address_space(3))) void*)l, 16, 0, 0);
}

// ---------------- prep: fp32 -> bf16 cast + row sum-of-squares ----------------
__global__ void prep_kernel(const float* __restrict__ gen, const float* __restrict__ pos,
                            unsigned short* __restrict__ gen_h, unsigned short* __restrict__ pos_h,
                            float* __restrict__ gn2, float* __restrict__ pn2) {
  int b = blockIdx.x;
  const float* src; unsigned short* dst; float* n2; int row;
  if (b < MROWS) { src = gen; dst = gen_h; n2 = gn2; row = b; }
  else           { src = pos; dst = pos_h; n2 = pn2; row = b - MROWS; }
  int t = threadIdx.x;
  float4 v = ((const float4*)(src + (size_t)row * DDIM))[t];
  float ss = v.x * v.x + v.y * v.y + v.z * v.z + v.w * v.w;
  ushort4 o;
  o.x = f2bf(v.x); o.y = f2bf(v.y); o.z = f2bf(v.z); o.w = f2bf(v.w);
  ((ushort4*)(dst + (size_t)row * DDIM))[t] = o;
#pragma unroll
  for (int m = 1; m < 64; m <<= 1) ss += __shfl_xor(ss, m);
  __shared__ float red[4];
  if ((t & 63) == 0) red[t >> 6] = ss;
  __syncthreads();
  if (t == 0) n2[row] = red[0] + red[1] + red[2] + red[3];
}

// ---------------- transpose: fp32 [8192][1024] -> bf16 [1024][8192] ----------------
__global__ void transpose_kernel(const float* __restrict__ gen, const float* __restrict__ pos,
                                 unsigned short* __restrict__ genT, unsigned short* __restrict__ posT) {
  __shared__ float tile[64][65];
  int b = blockIdx.x;
  const float* src; unsigned short* dst;
  if (b < 2048) { src = gen; dst = genT; }
  else          { src = pos; dst = posT; b -= 2048; }
  int tj = b >> 4, td = b & 15;
  int t = threadIdx.x;
#pragma unroll
  for (int it = 0; it < 16; ++it) {
    int idx = it * 256 + t;
    int r = idx >> 6, c = idx & 63;
    tile[r][c] = src[(size_t)(tj * 64 + r) * DDIM + td * 64 + c];
  }
  __syncthreads();
#pragma unroll
  for (int it = 0; it < 16; ++it) {
    int idx = it * 256 + t;
    int d = idx >> 6, j = idx & 63;
    dst[(size_t)(td * 64 + d) * MROWS + tj * 64 + j] = f2bf(tile[j][d]);
  }
}

// ---------------- merged-pipeline BT-GEMM: PassA(c) || PassB(c-1) in one dispatch ----------------
// Verified round-7 inner loop (128x128 tile, XOR-swizzled LDS, gl2lds16, ksteps=16).
// Role per block (uniform): decomposed gy < roleSplit -> PassA (score epilogue, P-write+lsum);
// gy >= roleSplit -> PassB (PV epilogue, O RMW). P double-buffered across dispatches so the
// two roles touch disjoint P buffers. Chunked y-fastest XCD swizzle (nwg always %8==0).
__launch_bounds__(256, 2)
__global__ void gemm_mrg(int roleSplit,
                         // PassA operands (chunk cA)
                         const unsigned short* __restrict__ Aa,   // gen_h
                         const unsigned short* __restrict__ Ba0,  // pos_h + j0A*DDIM
                         const unsigned short* __restrict__ Ba1,  // gen_h + j0A*DDIM
                         unsigned short* __restrict__ Pout0, unsigned short* __restrict__ Pout1,
                         int j0A,
                         const float* __restrict__ qn2,
                         const float* __restrict__ kn2a, const float* __restrict__ kn2b,
                         float* __restrict__ lsumA, float* __restrict__ lsumR,
                         // PassB operands (chunk cB)
                         const unsigned short* __restrict__ Pin0, const unsigned short* __restrict__ Pin1,
                         const unsigned short* __restrict__ Vt0,  // posT + j0B
                         const unsigned short* __restrict__ Vt1,  // genT + j0B
                         unsigned short* __restrict__ O0, unsigned short* __restrict__ O1,
                         int first) {
  __shared__ __align__(16) unsigned short Al[128 * 64];
  __shared__ __align__(16) unsigned short Bl[128 * 64];

  // ---- chunked XCD swizzle (T1), y-fastest decomposition
  const int NXB = gridDim.x, NYB = gridDim.y;                  // 64, 8 or 16
  const int nwg = NXB * NYB * gridDim.z;                       // 1024 or 2048 (%8==0)
  const int orig = blockIdx.x + NXB * (blockIdx.y + NYB * blockIdx.z);
  const int wid = (orig & 7) * (nwg >> 3) + (orig >> 3);
  const int gy = wid % NYB;
  const int bx = (wid / NYB) % NXB;
  const int bz = wid / (NYB * NXB);

  const int z = bz;
  const int role = (gy < roleSplit) ? 0 : 1;
  const int byl = role ? (gy - roleSplit) : gy;                // 0..7

  const unsigned short* A;
  const unsigned short* B;
  long lda, ldb;
  if (role == 0) { A = Aa;               B = z ? Ba1 : Ba0; lda = DDIM;  ldb = DDIM;  }
  else           { A = z ? Pin1 : Pin0;  B = z ? Vt1 : Vt0; lda = CHUNK; ldb = MROWS; }

  const int t = threadIdx.x;
  const int w = t >> 6, lane = t & 63, l15 = lane & 15, quad = lane >> 4;
  const int wm = w >> 1, wn = w & 1;
  const long m0 = (long)bx * 128;
  const long n0 = (long)byl * 128;
  const int trow = t >> 3;                       // 0..31
  const int tcol = (((t & 7) ^ (trow & 7)) * 8); // XOR-swizzled global 16B-unit

  f32x4 acc[4][4];
#pragma unroll
  for (int i = 0; i < 4; ++i)
#pragma unroll
    for (int j = 0; j < 4; ++j) acc[i][j] = (f32x4){0.f, 0.f, 0.f, 0.f};

  const unsigned short* Ab = A + (m0 + trow) * lda + tcol;
  const unsigned short* Bb = B + (n0 + trow) * ldb + tcol;
  unsigned short* Alw = Al + t * 8;  // lane-linear LDS dest (byte = t*16)
  unsigned short* Blw = Bl + t * 8;
  const int ue = (quad ^ (l15 & 7)) * 8;  // swizzled read unit (elems)

  for (int ks = 0; ks < DDIM / 64; ++ks) {   // 16 K-steps (K=1024 for both roles)
    const long ko = (long)ks * 64;
#pragma unroll
    for (int i = 0; i < 4; ++i) gl2lds16(Ab + (long)i * 32 * lda + ko, Alw + i * 2048);
#pragma unroll
    for (int i = 0; i < 4; ++i) gl2lds16(Bb + (long)i * 32 * ldb + ko, Blw + i * 2048);
    __syncthreads();
#pragma unroll
    for (int kk = 0; kk < 2; ++kk) {
      const int uo = ue ^ (kk * 32);
      bf16x8 af[4], bfr[4];
#pragma unroll
      for (int mi = 0; mi < 4; ++mi)
        af[mi] = *(const bf16x8*)(Al + (wm * 64 + mi * 16 + l15) * 64 + uo);
#pragma unroll
      for (int ni = 0; ni < 4; ++ni)
        bfr[ni] = *(const bf16x8*)(Bl + (wn * 64 + ni * 16 + l15) * 64 + uo);
#pragma unroll
      for (int mi = 0; mi < 4; ++mi)
#pragma unroll
        for (int ni = 0; ni < 4; ++ni)
          acc[mi][ni] = __builtin_amdgcn_mfma_f32_16x16x32_bf16(af[mi], bfr[ni], acc[mi][ni], 0, 0, 0);
    }
    __syncthreads();
  }

  if (role == 0) {
    unsigned short* Pout = z ? Pout1 : Pout0;
    const float* kn2 = z ? kn2b : kn2a;
    float* lsum = z ? lsumR : lsumA;
#pragma unroll
    for (int mi = 0; mi < 4; ++mi) {
      float rs[4] = {0.f, 0.f, 0.f, 0.f};
#pragma unroll
      for (int ni = 0; ni < 4; ++ni) {
        int c = (int)n0 + wn * 64 + ni * 16 + l15;  // chunk-local col
        float kn = kn2[j0A + c];
#pragma unroll
        for (int reg = 0; reg < 4; ++reg) {
          long r = m0 + wm * 64 + mi * 16 + quad * 4 + reg;  // C-layout: row = quad*4+reg
          float v = acc[mi][ni][reg];
          float d2 = qn2[r] + kn - 2.0f * v;
          float p = __expf(SHIFT_ - INV_T * sqrtf(fmaxf(d2, 0.0f)));
          if (z && (int)r == (j0A + c)) p = 0.0f;
          rs[reg] += p;
          Pout[r * (long)CHUNK + c] = f2bf(p);
        }
      }
#pragma unroll
      for (int reg = 0; reg < 4; ++reg) {
        float v = rs[reg];
        v += __shfl_xor(v, 1); v += __shfl_xor(v, 2);
        v += __shfl_xor(v, 4); v += __shfl_xor(v, 8);
        if (l15 == 0) atomicAdd(&lsum[m0 + wm * 64 + mi * 16 + quad * 4 + reg], v);
      }
    }
  } else {
    unsigned short* Oh = z ? O1 : O0;
#pragma unroll
    for (int mi = 0; mi < 4; ++mi)
#pragma unroll
      for (int ni = 0; ni < 4; ++ni) {
        long c = n0 + wn * 64 + ni * 16 + l15;
#pragma unroll
        for (int reg = 0; reg < 4; ++reg) {
          long r = m0 + wm * 64 + mi * 16 + quad * 4 + reg;
          long off = r * DDIM + c;
          float v = acc[mi][ni][reg];
          Oh[off] = f2bf(first ? v : (bf2f(Oh[off]) + v));
        }
      }
  }
}

// ---------------- merged epilogue: all four stats in one pass; 4 atomics/block ----------------
__global__ void epi_kernel(const unsigned short* __restrict__ OA, const unsigned short* __restrict__ OR_,
                           const float* __restrict__ lsumA, const float* __restrict__ lsumR,
                           const float* __restrict__ genf, float* __restrict__ gs) {
  __shared__ float wsL[4], wsD[4], wsA[4], wsR[4];
  const int t = threadIdx.x;
  const int w = t >> 6;
  const int lane = t & 63;
  float accL = 0.f, accD = 0.f, accA = 0.f, accR = 0.f;

  for (int i = 0; i < 8; ++i) {
    const int row = blockIdx.x * 32 + w * 8 + i;
    const float invlA = 1.0f / lsumA[row];
    const float invlR = 1.0f / lsumR[row];
    float ssA = 0.f, ssR = 0.f, ssD = 0.f;
#pragma unroll
    for (int u = 0; u < 4; ++u) {
      const long off = (long)row * DDIM + u * 256 + lane * 4;
      float4 g = *(const float4*)(genf + off);
      ushort4 oa = *(const ushort4*)(OA + off);
      ushort4 orr = *(const ushort4*)(OR_ + off);
      float g4[4] = {g.x, g.y, g.z, g.w};
      float a4[4] = {bf2f(oa.x), bf2f(oa.y), bf2f(oa.z), bf2f(oa.w)};
      float r4[4] = {bf2f(orr.x), bf2f(orr.y), bf2f(orr.z), bf2f(orr.w)};
#pragma unroll
      for (int e = 0; e < 4; ++e) {
        float a_ = a4[e] * invlA - g4[e];
        float r_ = r4[e] * invlR - g4[e];
        float d_ = a_ - r_;
        ssA += a_ * a_; ssR += r_ * r_; ssD += d_ * d_;
      }
    }
#pragma unroll
    for (int m = 1; m < 64; m <<= 1) {
      ssA += __shfl_xor(ssA, m);
      ssR += __shfl_xor(ssR, m);
      ssD += __shfl_xor(ssD, m);
    }
    accA += sqrtf(ssA); accR += sqrtf(ssR); accD += sqrtf(ssD); accL += ssD;
  }
  if (lane == 0) { wsL[w] = accL; wsD[w] = accD; wsA[w] = accA; wsR[w] = accR; }
  __syncthreads();
  if (t == 0) {
    atomicAdd(&gs[0], wsL[0] + wsL[1] + wsL[2] + wsL[3]);
    atomicAdd(&gs[1], wsD[0] + wsD[1] + wsD[2] + wsD[3]);
    atomicAdd(&gs[2], wsA[0] + wsA[1] + wsA[2] + wsA[3]);
    atomicAdd(&gs[3], wsR[0] + wsR[1] + wsR[2] + wsR[3]);
  }
}

__global__ void finalize_kernel(const float* __restrict__ gs, float* __restrict__ out) {
  int t = threadIdx.x;
  if (t == 0) out[0] = gs[0] / (8192.0f * 1024.0f);
  if (t == 1) out[1] = gs[1] / 8192.0f;
  if (t == 2) out[2] = gs[2] / 8192.0f;
  if (t == 3) out[3] = gs[3] / 8192.0f;
}

extern "C" void kernel_launch(void* const* d_in, const int* in_sizes, int n_in,
                              void* d_out, int out_size, void* d_ws, size_t ws_size,
                              hipStream_t stream) {
  const float* gen = (const float*)d_in[0];
  const float* pos = (const float*)d_in[1];
  char* ws = (char*)d_ws;
  const size_t MB = (size_t)1 << 20;
  const size_t need_pipe = 160 * MB + 4 * 32768 + 64;

  // common small buffers appended after the big region
  if (ws_size >= need_pipe) {
    // ---------------- pipelined path: PassA(c) || PassB(c-1), P double-buffered ----------------
    unsigned short* gen_h = (unsigned short*)(ws + 0 * MB);    // 16 MB
    unsigned short* pos_h = (unsigned short*)(ws + 16 * MB);   // 16 MB
    unsigned short* genT  = (unsigned short*)(ws + 32 * MB);   // 16 MB
    unsigned short* posT  = (unsigned short*)(ws + 48 * MB);   // 16 MB
    unsigned short* Pa[2] = {(unsigned short*)(ws + 64 * MB),  (unsigned short*)(ws + 80 * MB)};
    unsigned short* Pr[2] = {(unsigned short*)(ws + 96 * MB),  (unsigned short*)(ws + 112 * MB)};
    unsigned short* OhA   = (unsigned short*)(ws + 128 * MB);  // 16 MB
    unsigned short* OhR   = (unsigned short*)(ws + 144 * MB);  // 16 MB
    float* gn2   = (float*)(ws + 160 * MB);
    float* pn2   = (float*)(ws + 160 * MB + 32768);
    float* lsumA = (float*)(ws + 160 * MB + 65536);
    float* lsumR = (float*)(ws + 160 * MB + 98304);
    float* gs    = (float*)(ws + 160 * MB + 131072);

    hipMemsetAsync(gs, 0, 4 * sizeof(float), stream);
    hipMemsetAsync(lsumA, 0, 2 * MROWS * sizeof(float), stream);
    prep_kernel<<<dim3(16384), dim3(256), 0, stream>>>(gen, pos, gen_h, pos_h, gn2, pn2);
    transpose_kernel<<<dim3(4096), dim3(256), 0, stream>>>(gen, pos, genT, posT);

    const int nchunks = MROWS / CHUNK;  // 8
    // D0: pure PassA(0)
    gemm_mrg<<<dim3(64, 8, 2), dim3(256), 0, stream>>>(
        8, gen_h, pos_h, gen_h, Pa[0], Pr[0], 0, gn2, pn2, gn2, lsumA, lsumR,
        Pa[0], Pr[0], posT, genT, OhA, OhR, 0);
    // D1..D7: PassA(c) || PassB(c-1)
    for (int c = 1; c < nchunks; ++c) {
      const int j0A = c * CHUNK, j0B = (c - 1) * CHUNK;
      gemm_mrg<<<dim3(64, 16, 2), dim3(256), 0, stream>>>(
          8, gen_h, pos_h + (long)j0A * DDIM, gen_h + (long)j0A * DDIM,
          Pa[c & 1], Pr[c & 1], j0A, gn2, pn2, gn2, lsumA, lsumR,
          Pa[(c - 1) & 1], Pr[(c - 1) & 1], posT + j0B, genT + j0B, OhA, OhR, (c == 1));
    }
    // D8: pure PassB(7)
    {
      const int c = nchunks - 1;
      gemm_mrg<<<dim3(64, 8, 2), dim3(256), 0, stream>>>(
          0, gen_h, pos_h, gen_h, Pa[c & 1], Pr[c & 1], 0, gn2, pn2, gn2, lsumA, lsumR,
          Pa[c & 1], Pr[c & 1], posT + (long)c * CHUNK, genT + (long)c * CHUNK, OhA, OhR, 0);
    }

    epi_kernel<<<dim3(256), dim3(256), 0, stream>>>(OhA, OhR, lsumA, lsumR, gen, gs);
    finalize_kernel<<<dim3(1), dim3(64), 0, stream>>>(gs, (float*)d_out);
  } else {
    // ---------------- fallback: round-7 serial chunked path (verified, ~910 us) ----------------
    unsigned short* gen_h = (unsigned short*)(ws + 0 * MB);
    unsigned short* pos_h = (unsigned short*)(ws + 16 * MB);
    unsigned short* genT  = (unsigned short*)(ws + 32 * MB);
    unsigned short* posT  = (unsigned short*)(ws + 48 * MB);
    unsigned short* Pa    = (unsigned short*)(ws + 64 * MB);
    unsigned short* Pr    = (unsigned short*)(ws + 80 * MB);
    unsigned short* OhA   = (unsigned short*)(ws + 96 * MB);
    unsigned short* OhR   = (unsigned short*)(ws + 112 * MB);
    float* gn2   = (float*)(ws + 128 * MB);
    float* pn2   = (float*)(ws + 128 * MB + 32768);
    float* lsumA = (float*)(ws + 128 * MB + 65536);
    float* lsumR = (float*)(ws + 128 * MB + 98304);
    float* gs    = (float*)(ws + 128 * MB + 131072);

    hipMemsetAsync(gs, 0, 4 * sizeof(float), stream);
    hipMemsetAsync(lsumA, 0, 2 * MROWS * sizeof(float), stream);
    prep_kernel<<<dim3(16384), dim3(256), 0, stream>>>(gen, pos, gen_h, pos_h, gn2, pn2);
    transpose_kernel<<<dim3(4096), dim3(256), 0, stream>>>(gen, pos, genT, posT);

    const int nchunks = MROWS / CHUNK;
    for (int c = 0; c < nchunks; ++c) {
      const int j0 = c * CHUNK;
      // PassA(c): pure role-0 dispatch writing chunk into Pa/Pr
      gemm_mrg<<<dim3(64, 8, 2), dim3(256), 0, stream>>>(
          8, gen_h, pos_h + (long)j0 * DDIM, gen_h + (long)j0 * DDIM,
          Pa, Pr, j0, gn2, pn2, gn2, lsumA, lsumR,
          Pa, Pr, posT, genT, OhA, OhR, 0);
      // PassB(c): pure role-1 dispatch accumulating O
      gemm_mrg<<<dim3(64, 8, 2), dim3(256), 0, stream>>>(
          0, gen_h, pos_h, gen_h, Pa, Pr, 0, gn2, pn2, gn2, lsumA, lsumR,
          Pa, Pr, posT + j0, genT + j0, OhA, OhR, (c == 0));
    }

    epi_kernel<<<dim3(256), dim3(256), 0, stream>>>(OhA, OhR, lsumA, lsumR, gen, gs);
    finalize_kernel<<<dim3(1), dim3(64), 0, stream>>>(gs, (float*)d_out);
  }
}

// Round 10
// 814.157 us; speedup vs baseline: 1.2535x; 1.0993x over previous
//
#include <hip/hip_runtime.h>
#include <stdint.h>

#define INV_T 10.0f
#define SHIFT_ 460.0f
#define MROWS 8192
#define DDIM 1024
#define CHUNK 1024

typedef __attribute__((ext_vector_type(8))) short bf16x8;
typedef __attribute__((ext_vector_type(4))) float f32x4;

__device__ __forceinline__ float bf2f(unsigned short u) {
  return __uint_as_float(((unsigned int)u) << 16);
}
__device__ __forceinline__ unsigned short f2bf(float f) {
  unsigned int u = __float_as_uint(f);
  return (unsigned short)((u + 0x7FFFu + ((u >> 16) & 1u)) >> 16);
}
__device__ __forceinline__ void gl2lds16(const unsigned short* g, unsigned short* l) {
  __builtin_amdgcn_global_load_lds((const __attribute__((address_space(1))) void*)g,
                                   (__attribute__((address_space(3))) void*)l, 16, 0, 0);
}

// ---------------- prep: fp32 -> bf16 cast + row sum-of-squares ----------------
__global__ void prep_kernel(const float* __restrict__ gen, const float* __restrict__ pos,
                            unsigned short* __restrict__ gen_h, unsigned short* __restrict__ pos_h,
                            float* __restrict__ gn2, float* __restrict__ pn2) {
  int b = blockIdx.x;
  const float* src; unsigned short* dst; float* n2; int row;
  if (b < MROWS) { src = gen; dst = gen_h; n2 = gn2; row = b; }
  else           { src = pos; dst = pos_h; n2 = pn2; row = b - MROWS; }
  int t = threadIdx.x;
  float4 v = ((const float4*)(src + (size_t)row * DDIM))[t];
  float ss = v.x * v.x + v.y * v.y + v.z * v.z + v.w * v.w;
  ushort4 o;
  o.x = f2bf(v.x); o.y = f2bf(v.y); o.z = f2bf(v.z); o.w = f2bf(v.w);
  ((ushort4*)(dst + (size_t)row * DDIM))[t] = o;
#pragma unroll
  for (int m = 1; m < 64; m <<= 1) ss += __shfl_xor(ss, m);
  __shared__ float red[4];
  if ((t & 63) == 0) red[t >> 6] = ss;
  __syncthreads();
  if (t == 0) n2[row] = red[0] + red[1] + red[2] + red[3];
}

// ---------------- transpose: fp32 [8192][1024] -> bf16 [1024][8192] ----------------
__global__ void transpose_kernel(const float* __restrict__ gen, const float* __restrict__ pos,
                                 unsigned short* __restrict__ genT, unsigned short* __restrict__ posT) {
  __shared__ float tile[64][65];
  int b = blockIdx.x;
  const float* src; unsigned short* dst;
  if (b < 2048) { src = gen; dst = genT; }
  else          { src = pos; dst = posT; b -= 2048; }
  int tj = b >> 4, td = b & 15;
  int t = threadIdx.x;
#pragma unroll
  for (int it = 0; it < 16; ++it) {
    int idx = it * 256 + t;
    int r = idx >> 6, c = idx & 63;
    tile[r][c] = src[(size_t)(tj * 64 + r) * DDIM + td * 64 + c];
  }
  __syncthreads();
#pragma unroll
  for (int it = 0; it < 16; ++it) {
    int idx = it * 256 + t;
    int d = idx >> 6, j = idx & 63;
    dst[(size_t)(td * 64 + d) * MROWS + tj * 64 + j] = f2bf(tile[j][d]);
  }
}

// ---------------- score GEMM, z-FUSED: both streams share the A panel ----------------
// One block computes S_attr and S_rep 128x128 tiles for the same (m0,n0): stage A once +
// both B panels (LDS 48KB), 64 MFMA per barrier-pair (2x the verified loop's density).
// Grid (64,8)=512 blocks = 2/CU in one round. Epilogue = verified EPI-0 body, run twice.
__launch_bounds__(256, 2)
__global__ void gemm_sc(const unsigned short* __restrict__ Aq,    // gen_h
                        const unsigned short* __restrict__ Bka,   // pos_h + j0*DDIM
                        const unsigned short* __restrict__ Bkr,   // gen_h + j0*DDIM
                        unsigned short* __restrict__ Pa, unsigned short* __restrict__ Pr,
                        int j0,
                        const float* __restrict__ gn2, const float* __restrict__ pn2,
                        float* __restrict__ lsumA, float* __restrict__ lsumR) {
  __shared__ __align__(16) unsigned short Al[128 * 64];
  __shared__ __align__(16) unsigned short Bal[128 * 64];
  __shared__ __align__(16) unsigned short Brl[128 * 64];

  // chunked XCD swizzle (nwg=512, %8==0), y-fastest
  const int orig = blockIdx.x + 64 * blockIdx.y;
  const int wid = (orig & 7) * 64 + (orig >> 3);
  const int by = wid & 7;
  const int bx = wid >> 3;

  const int t = threadIdx.x;
  const int w = t >> 6, lane = t & 63, l15 = lane & 15, quad = lane >> 4;
  const int wm = w >> 1, wn = w & 1;
  const long m0 = (long)bx * 128;
  const long n0 = (long)by * 128;
  const int trow = t >> 3;                       // 0..31
  const int tcol = (((t & 7) ^ (trow & 7)) * 8); // XOR-swizzled global 16B-unit

  f32x4 accA[4][4], accR[4][4];
#pragma unroll
  for (int i = 0; i < 4; ++i)
#pragma unroll
    for (int j = 0; j < 4; ++j) {
      accA[i][j] = (f32x4){0.f, 0.f, 0.f, 0.f};
      accR[i][j] = (f32x4){0.f, 0.f, 0.f, 0.f};
    }

  const unsigned short* Ab  = Aq  + (m0 + trow) * DDIM + tcol;
  const unsigned short* Bab = Bka + (n0 + trow) * DDIM + tcol;
  const unsigned short* Brb = Bkr + (n0 + trow) * DDIM + tcol;
  unsigned short* Alw = Al  + t * 8;  // lane-linear LDS dest
  unsigned short* Baw = Bal + t * 8;
  unsigned short* Brw = Brl + t * 8;
  const int ue = (quad ^ (l15 & 7)) * 8;  // swizzled read unit (elems)

  for (int ks = 0; ks < DDIM / 64; ++ks) {
    const long ko = (long)ks * 64;
#pragma unroll
    for (int i = 0; i < 4; ++i) gl2lds16(Ab + (long)i * 32 * DDIM + ko, Alw + i * 2048);
#pragma unroll
    for (int i = 0; i < 4; ++i) gl2lds16(Bab + (long)i * 32 * DDIM + ko, Baw + i * 2048);
#pragma unroll
    for (int i = 0; i < 4; ++i) gl2lds16(Brb + (long)i * 32 * DDIM + ko, Brw + i * 2048);
    __syncthreads();
#pragma unroll
    for (int kk = 0; kk < 2; ++kk) {
      const int uo = ue ^ (kk * 32);
      bf16x8 af[4], ba[4], br[4];
#pragma unroll
      for (int mi = 0; mi < 4; ++mi)
        af[mi] = *(const bf16x8*)(Al + (wm * 64 + mi * 16 + l15) * 64 + uo);
#pragma unroll
      for (int ni = 0; ni < 4; ++ni) {
        ba[ni] = *(const bf16x8*)(Bal + (wn * 64 + ni * 16 + l15) * 64 + uo);
        br[ni] = *(const bf16x8*)(Brl + (wn * 64 + ni * 16 + l15) * 64 + uo);
      }
#pragma unroll
      for (int mi = 0; mi < 4; ++mi)
#pragma unroll
        for (int ni = 0; ni < 4; ++ni) {
          accA[mi][ni] = __builtin_amdgcn_mfma_f32_16x16x32_bf16(af[mi], ba[ni], accA[mi][ni], 0, 0, 0);
          accR[mi][ni] = __builtin_amdgcn_mfma_f32_16x16x32_bf16(af[mi], br[ni], accR[mi][ni], 0, 0, 0);
        }
    }
    __syncthreads();
  }

  // ---- epilogue: attraction (no diag), then repulsion (diag masked) — verified EPI-0 body
#pragma unroll
  for (int mi = 0; mi < 4; ++mi) {
    float rs[4] = {0.f, 0.f, 0.f, 0.f};
#pragma unroll
    for (int ni = 0; ni < 4; ++ni) {
      int c = (int)n0 + wn * 64 + ni * 16 + l15;
      float kn = pn2[j0 + c];
#pragma unroll
      for (int reg = 0; reg < 4; ++reg) {
        long r = m0 + wm * 64 + mi * 16 + quad * 4 + reg;
        float v = accA[mi][ni][reg];
        float d2 = gn2[r] + kn - 2.0f * v;
        float p = __expf(SHIFT_ - INV_T * sqrtf(fmaxf(d2, 0.0f)));
        rs[reg] += p;
        Pa[r * (long)CHUNK + c] = f2bf(p);
      }
    }
#pragma unroll
    for (int reg = 0; reg < 4; ++reg) {
      float v = rs[reg];
      v += __shfl_xor(v, 1); v += __shfl_xor(v, 2);
      v += __shfl_xor(v, 4); v += __shfl_xor(v, 8);
      if (l15 == 0) atomicAdd(&lsumA[m0 + wm * 64 + mi * 16 + quad * 4 + reg], v);
    }
  }
#pragma unroll
  for (int mi = 0; mi < 4; ++mi) {
    float rs[4] = {0.f, 0.f, 0.f, 0.f};
#pragma unroll
    for (int ni = 0; ni < 4; ++ni) {
      int c = (int)n0 + wn * 64 + ni * 16 + l15;
      float kn = gn2[j0 + c];
#pragma unroll
      for (int reg = 0; reg < 4; ++reg) {
        long r = m0 + wm * 64 + mi * 16 + quad * 4 + reg;
        float v = accR[mi][ni][reg];
        float d2 = gn2[r] + kn - 2.0f * v;
        float p = __expf(SHIFT_ - INV_T * sqrtf(fmaxf(d2, 0.0f)));
        if ((int)r == (j0 + c)) p = 0.0f;
        rs[reg] += p;
        Pr[r * (long)CHUNK + c] = f2bf(p);
      }
    }
#pragma unroll
    for (int reg = 0; reg < 4; ++reg) {
      float v = rs[reg];
      v += __shfl_xor(v, 1); v += __shfl_xor(v, 2);
      v += __shfl_xor(v, 4); v += __shfl_xor(v, 8);
      if (l15 == 0) atomicAdd(&lsumR[m0 + wm * 64 + mi * 16 + quad * 4 + reg], v);
    }
  }
}

// ---------------- PV GEMM, j-PAIR-FUSED: two chunks accumulate in registers ----------------
// 32 K-steps per block (two back-to-back 16-step segments over P[c0]@V[c0], P[c1]@V[c1]);
// O RMW per PAIR instead of per chunk. Grid (64,8,2)=1024 blocks.
#define KSEG(Abase, Bbase, LDA_, LDB_)                                                     \
  {                                                                                        \
    const unsigned short* Ab_ = (Abase) + (m0 + trow) * (LDA_) + tcol;                     \
    const unsigned short* Bb_ = (Bbase) + (n0 + trow) * (LDB_) + tcol;                     \
    for (int ks = 0; ks < 16; ++ks) {                                                      \
      const long ko = (long)ks * 64;                                                       \
      _Pragma("unroll")                                                                    \
      for (int i = 0; i < 4; ++i) gl2lds16(Ab_ + (long)i * 32 * (LDA_) + ko, Alw + i * 2048); \
      _Pragma("unroll")                                                                    \
      for (int i = 0; i < 4; ++i) gl2lds16(Bb_ + (long)i * 32 * (LDB_) + ko, Blw + i * 2048); \
      __syncthreads();                                                                     \
      _Pragma("unroll")                                                                    \
      for (int kk = 0; kk < 2; ++kk) {                                                     \
        const int uo = ue ^ (kk * 32);                                                     \
        bf16x8 af[4], bfr[4];                                                              \
        _Pragma("unroll")                                                                  \
        for (int mi = 0; mi < 4; ++mi)                                                     \
          af[mi] = *(const bf16x8*)(Al + (wm * 64 + mi * 16 + l15) * 64 + uo);             \
        _Pragma("unroll")                                                                  \
        for (int ni = 0; ni < 4; ++ni)                                                     \
          bfr[ni] = *(const bf16x8*)(Bl + (wn * 64 + ni * 16 + l15) * 64 + uo);            \
        _Pragma("unroll")                                                                  \
        for (int mi = 0; mi < 4; ++mi)                                                     \
          _Pragma("unroll")                                                                \
          for (int ni = 0; ni < 4; ++ni)                                                   \
            acc[mi][ni] = __builtin_amdgcn_mfma_f32_16x16x32_bf16(af[mi], bfr[ni], acc[mi][ni], 0, 0, 0); \
      }                                                                                    \
      __syncthreads();                                                                     \
    }                                                                                      \
  }

__launch_bounds__(256, 2)
__global__ void gemm_pv(const unsigned short* __restrict__ Pa0, const unsigned short* __restrict__ Pr0,
                        const unsigned short* __restrict__ Pa1, const unsigned short* __restrict__ Pr1,
                        const unsigned short* __restrict__ Va0, const unsigned short* __restrict__ Vr0,
                        const unsigned short* __restrict__ Va1, const unsigned short* __restrict__ Vr1,
                        unsigned short* __restrict__ OA, unsigned short* __restrict__ OR_,
                        int first) {
  __shared__ __align__(16) unsigned short Al[128 * 64];
  __shared__ __align__(16) unsigned short Bl[128 * 64];

  // chunked XCD swizzle (nwg=1024, %8==0), y-fastest
  const int orig = blockIdx.x + 64 * (blockIdx.y + 8 * blockIdx.z);
  const int wid = (orig & 7) * 128 + (orig >> 3);
  const int by = wid & 7;
  const int bx = (wid >> 3) & 63;
  const int z = wid >> 9;

  const unsigned short* A0 = z ? Pr0 : Pa0;
  const unsigned short* B0 = z ? Vr0 : Va0;
  const unsigned short* A1 = z ? Pr1 : Pa1;
  const unsigned short* B1 = z ? Vr1 : Va1;

  const int t = threadIdx.x;
  const int w = t >> 6, lane = t & 63, l15 = lane & 15, quad = lane >> 4;
  const int wm = w >> 1, wn = w & 1;
  const long m0 = (long)bx * 128;
  const long n0 = (long)by * 128;
  const int trow = t >> 3;
  const int tcol = (((t & 7) ^ (trow & 7)) * 8);

  f32x4 acc[4][4];
#pragma unroll
  for (int i = 0; i < 4; ++i)
#pragma unroll
    for (int j = 0; j < 4; ++j) acc[i][j] = (f32x4){0.f, 0.f, 0.f, 0.f};

  unsigned short* Alw = Al + t * 8;
  unsigned short* Blw = Bl + t * 8;
  const int ue = (quad ^ (l15 & 7)) * 8;

  KSEG(A0, B0, CHUNK, MROWS);
  KSEG(A1, B1, CHUNK, MROWS);

  unsigned short* Oh = z ? OR_ : OA;
#pragma unroll
  for (int mi = 0; mi < 4; ++mi)
#pragma unroll
    for (int ni = 0; ni < 4; ++ni) {
      long c = n0 + wn * 64 + ni * 16 + l15;
#pragma unroll
      for (int reg = 0; reg < 4; ++reg) {
        long r = m0 + wm * 64 + mi * 16 + quad * 4 + reg;
        long off = r * DDIM + c;
        float v = acc[mi][ni][reg];
        Oh[off] = f2bf(first ? v : (bf2f(Oh[off]) + v));
      }
    }
}
#undef KSEG

// ---------------- merged epilogue: all four stats in one pass; 4 atomics/block ----------------
__global__ void epi_kernel(const unsigned short* __restrict__ OA, const unsigned short* __restrict__ OR_,
                           const float* __restrict__ lsumA, const float* __restrict__ lsumR,
                           const float* __restrict__ genf, float* __restrict__ gs) {
  __shared__ float wsL[4], wsD[4], wsA[4], wsR[4];
  const int t = threadIdx.x;
  const int w = t >> 6;
  const int lane = t & 63;
  float accL = 0.f, accD = 0.f, accA = 0.f, accR = 0.f;

  for (int i = 0; i < 8; ++i) {
    const int row = blockIdx.x * 32 + w * 8 + i;
    const float invlA = 1.0f / lsumA[row];
    const float invlR = 1.0f / lsumR[row];
    float ssA = 0.f, ssR = 0.f, ssD = 0.f;
#pragma unroll
    for (int u = 0; u < 4; ++u) {
      const long off = (long)row * DDIM + u * 256 + lane * 4;
      float4 g = *(const float4*)(genf + off);
      ushort4 oa = *(const ushort4*)(OA + off);
      ushort4 orr = *(const ushort4*)(OR_ + off);
      float g4[4] = {g.x, g.y, g.z, g.w};
      float a4[4] = {bf2f(oa.x), bf2f(oa.y), bf2f(oa.z), bf2f(oa.w)};
      float r4[4] = {bf2f(orr.x), bf2f(orr.y), bf2f(orr.z), bf2f(orr.w)};
#pragma unroll
      for (int e = 0; e < 4; ++e) {
        float a_ = a4[e] * invlA - g4[e];
        float r_ = r4[e] * invlR - g4[e];
        float d_ = a_ - r_;
        ssA += a_ * a_; ssR += r_ * r_; ssD += d_ * d_;
      }
    }
#pragma unroll
    for (int m = 1; m < 64; m <<= 1) {
      ssA += __shfl_xor(ssA, m);
      ssR += __shfl_xor(ssR, m);
      ssD += __shfl_xor(ssD, m);
    }
    accA += sqrtf(ssA); accR += sqrtf(ssR); accD += sqrtf(ssD); accL += ssD;
  }
  if (lane == 0) { wsL[w] = accL; wsD[w] = accD; wsA[w] = accA; wsR[w] = accR; }
  __syncthreads();
  if (t == 0) {
    atomicAdd(&gs[0], wsL[0] + wsL[1] + wsL[2] + wsL[3]);
    atomicAdd(&gs[1], wsD[0] + wsD[1] + wsD[2] + wsD[3]);
    atomicAdd(&gs[2], wsA[0] + wsA[1] + wsA[2] + wsA[3]);
    atomicAdd(&gs[3], wsR[0] + wsR[1] + wsR[2] + wsR[3]);
  }
}

__global__ void finalize_kernel(const float* __restrict__ gs, float* __restrict__ out) {
  int t = threadIdx.x;
  if (t == 0) out[0] = gs[0] / (8192.0f * 1024.0f);
  if (t == 1) out[1] = gs[1] / 8192.0f;
  if (t == 2) out[2] = gs[2] / 8192.0f;
  if (t == 3) out[3] = gs[3] / 8192.0f;
}

extern "C" void kernel_launch(void* const* d_in, const int* in_sizes, int n_in,
                              void* d_out, int out_size, void* d_ws, size_t ws_size,
                              hipStream_t stream) {
  const float* gen = (const float*)d_in[0];
  const float* pos = (const float*)d_in[1];
  char* ws = (char*)d_ws;
  const size_t MB = (size_t)1 << 20;
  // layout (proven budget: ws >= 160MB + 131136 from round 9)
  unsigned short* gen_h = (unsigned short*)(ws + 0 * MB);    // 16 MB
  unsigned short* pos_h = (unsigned short*)(ws + 16 * MB);   // 16 MB
  unsigned short* genT  = (unsigned short*)(ws + 32 * MB);   // 16 MB
  unsigned short* posT  = (unsigned short*)(ws + 48 * MB);   // 16 MB
  unsigned short* Pa0   = (unsigned short*)(ws + 64 * MB);   // 16 MB
  unsigned short* Pr0   = (unsigned short*)(ws + 80 * MB);   // 16 MB
  unsigned short* Pa1   = (unsigned short*)(ws + 96 * MB);   // 16 MB
  unsigned short* Pr1   = (unsigned short*)(ws + 112 * MB);  // 16 MB
  unsigned short* OhA   = (unsigned short*)(ws + 128 * MB);  // 16 MB
  unsigned short* OhR   = (unsigned short*)(ws + 144 * MB);  // 16 MB
  float* gn2   = (float*)(ws + 160 * MB);
  float* pn2   = (float*)(ws + 160 * MB + 32768);
  float* lsumA = (float*)(ws + 160 * MB + 65536);
  float* lsumR = (float*)(ws + 160 * MB + 98304);
  float* gs    = (float*)(ws + 160 * MB + 131072);

  hipMemsetAsync(gs, 0, 4 * sizeof(float), stream);
  hipMemsetAsync(lsumA, 0, 2 * MROWS * sizeof(float), stream);  // lsumA + lsumR contiguous
  prep_kernel<<<dim3(16384), dim3(256), 0, stream>>>(gen, pos, gen_h, pos_h, gn2, pn2);
  transpose_kernel<<<dim3(4096), dim3(256), 0, stream>>>(gen, pos, genT, posT);

  for (int p = 0; p < 4; ++p) {
    const int j00 = (2 * p) * CHUNK, j01 = (2 * p + 1) * CHUNK;
    gemm_sc<<<dim3(64, 8), dim3(256), 0, stream>>>(
        gen_h, pos_h + (long)j00 * DDIM, gen_h + (long)j00 * DDIM,
        Pa0, Pr0, j00, gn2, pn2, lsumA, lsumR);
    gemm_sc<<<dim3(64, 8), dim3(256), 0, stream>>>(
        gen_h, pos_h + (long)j01 * DDIM, gen_h + (long)j01 * DDIM,
        Pa1, Pr1, j01, gn2, pn2, lsumA, lsumR);
    gemm_pv<<<dim3(64, 8, 2), dim3(256), 0, stream>>>(
        Pa0, Pr0, Pa1, Pr1,
        posT + j00, genT + j00, posT + j01, genT + j01,
        OhA, OhR, p == 0);
  }

  epi_kernel<<<dim3(256), dim3(256), 0, stream>>>(OhA, OhR, lsumA, lsumR, gen, gs);
  finalize_kernel<<<dim3(1), dim3(64), 0, stream>>>(gs, (float*)d_out);
}

// Round 11
// 803.135 us; speedup vs baseline: 1.2707x; 1.0137x over previous
//
#include <hip/hip_runtime.h>
#include <stdint.h>

#define INV_T 10.0f
#define SHIFT_ 460.0f
#define MROWS 8192
#define DDIM 1024
#define CHUNK 1024

typedef __attribute__((ext_vector_type(8))) short bf16x8;
typedef __attribute__((ext_vector_type(4))) float f32x4;

__device__ __forceinline__ float bf2f(unsigned short u) {
  return __uint_as_float(((unsigned int)u) << 16);
}
__device__ __forceinline__ unsigned short f2bf(float f) {
  unsigned int u = __float_as_uint(f);
  return (unsigned short)((u + 0x7FFFu + ((u >> 16) & 1u)) >> 16);
}
__device__ __forceinline__ void gl2lds16(const unsigned short* g, unsigned short* l) {
  __builtin_amdgcn_global_load_lds((const __attribute__((address_space(1))) void*)g,
                                   (__attribute__((address_space(3))) void*)l, 16, 0, 0);
}

// ---------------- prep: fp32 -> bf16 cast + row sum-of-squares ----------------
__global__ void prep_kernel(const float* __restrict__ gen, const float* __restrict__ pos,
                            unsigned short* __restrict__ gen_h, unsigned short* __restrict__ pos_h,
                            float* __restrict__ gn2, float* __restrict__ pn2) {
  int b = blockIdx.x;
  const float* src; unsigned short* dst; float* n2; int row;
  if (b < MROWS) { src = gen; dst = gen_h; n2 = gn2; row = b; }
  else           { src = pos; dst = pos_h; n2 = pn2; row = b - MROWS; }
  int t = threadIdx.x;
  float4 v = ((const float4*)(src + (size_t)row * DDIM))[t];
  float ss = v.x * v.x + v.y * v.y + v.z * v.z + v.w * v.w;
  ushort4 o;
  o.x = f2bf(v.x); o.y = f2bf(v.y); o.z = f2bf(v.z); o.w = f2bf(v.w);
  ((ushort4*)(dst + (size_t)row * DDIM))[t] = o;
#pragma unroll
  for (int m = 1; m < 64; m <<= 1) ss += __shfl_xor(ss, m);
  __shared__ float red[4];
  if ((t & 63) == 0) red[t >> 6] = ss;
  __syncthreads();
  if (t == 0) n2[row] = red[0] + red[1] + red[2] + red[3];
}

// ---------------- transpose: fp32 [8192][1024] -> bf16 [1024][8192] ----------------
__global__ void transpose_kernel(const float* __restrict__ gen, const float* __restrict__ pos,
                                 unsigned short* __restrict__ genT, unsigned short* __restrict__ posT) {
  __shared__ float tile[64][65];
  int b = blockIdx.x;
  const float* src; unsigned short* dst;
  if (b < 2048) { src = gen; dst = genT; }
  else          { src = pos; dst = posT; b -= 2048; }
  int tj = b >> 4, td = b & 15;
  int t = threadIdx.x;
#pragma unroll
  for (int it = 0; it < 16; ++it) {
    int idx = it * 256 + t;
    int r = idx >> 6, c = idx & 63;
    tile[r][c] = src[(size_t)(tj * 64 + r) * DDIM + td * 64 + c];
  }
  __syncthreads();
#pragma unroll
  for (int it = 0; it < 16; ++it) {
    int idx = it * 256 + t;
    int d = idx >> 6, j = idx & 63;
    dst[(size_t)(td * 64 + d) * MROWS + tj * 64 + j] = f2bf(tile[j][d]);
  }
}

// ---------------- BT-GEMM (verified round-7/8 form): 128x128, XOR-swizzled LDS, z=2 ----------------
// Used here only as EPI=0 (score pass): measured 53 us/chunk, MfmaUtil ~26%.
template <int EPI>
__launch_bounds__(256, 2)
__global__ void gemm_bt(const unsigned short* __restrict__ A0, const unsigned short* __restrict__ A1,
                        long lda,
                        const unsigned short* __restrict__ B0, const unsigned short* __restrict__ B1,
                        long ldb, int ksteps,
                        unsigned short* __restrict__ P0, unsigned short* __restrict__ P1,
                        int pld, int j0,
                        const float* __restrict__ qn2,
                        const float* __restrict__ kn2a, const float* __restrict__ kn2b,
                        float* __restrict__ lsum0, float* __restrict__ lsum1,
                        unsigned short* __restrict__ O0, unsigned short* __restrict__ O1,
                        int first) {
  __shared__ __align__(16) unsigned short Al[128 * 64];
  __shared__ __align__(16) unsigned short Bl[128 * 64];

  const int NXB = gridDim.x, NYB = gridDim.y;
  const int nwg = NXB * NYB * gridDim.z;                       // %8==0 in all launches
  const int orig = blockIdx.x + NXB * (blockIdx.y + NYB * blockIdx.z);
  const int wid = (orig & 7) * (nwg >> 3) + (orig >> 3);
  int bx, by, bz;
  by = wid % NYB;
  bx = (wid / NYB) % NXB;
  bz = wid / (NYB * NXB);

  const int z = bz;
  const unsigned short* A = z ? A1 : A0;
  const unsigned short* B = z ? B1 : B0;
  const int t = threadIdx.x;
  const int w = t >> 6, lane = t & 63, l15 = lane & 15, quad = lane >> 4;
  const int wm = w >> 1, wn = w & 1;
  const long m0 = (long)bx * 128;
  const long n0 = (long)by * 128;
  const int trow = t >> 3;                       // 0..31
  const int tcol = (((t & 7) ^ (trow & 7)) * 8); // XOR-swizzled global 16B-unit

  f32x4 acc[4][4];
#pragma unroll
  for (int i = 0; i < 4; ++i)
#pragma unroll
    for (int j = 0; j < 4; ++j) acc[i][j] = (f32x4){0.f, 0.f, 0.f, 0.f};

  const unsigned short* Ab = A + (m0 + trow) * lda + tcol;
  const unsigned short* Bb = B + (n0 + trow) * ldb + tcol;
  unsigned short* Alw = Al + t * 8;  // lane-linear LDS dest (byte = t*16)
  unsigned short* Blw = Bl + t * 8;
  const int ue = (quad ^ (l15 & 7)) * 8;  // swizzled read unit (elems)

  for (int ks = 0; ks < ksteps; ++ks) {
    const long ko = (long)ks * 64;
#pragma unroll
    for (int i = 0; i < 4; ++i) gl2lds16(Ab + (long)i * 32 * lda + ko, Alw + i * 2048);
#pragma unroll
    for (int i = 0; i < 4; ++i) gl2lds16(Bb + (long)i * 32 * ldb + ko, Blw + i * 2048);
    __syncthreads();
#pragma unroll
    for (int kk = 0; kk < 2; ++kk) {
      const int uo = ue ^ (kk * 32);
      bf16x8 af[4], bfr[4];
#pragma unroll
      for (int mi = 0; mi < 4; ++mi)
        af[mi] = *(const bf16x8*)(Al + (wm * 64 + mi * 16 + l15) * 64 + uo);
#pragma unroll
      for (int ni = 0; ni < 4; ++ni)
        bfr[ni] = *(const bf16x8*)(Bl + (wn * 64 + ni * 16 + l15) * 64 + uo);
#pragma unroll
      for (int mi = 0; mi < 4; ++mi)
#pragma unroll
        for (int ni = 0; ni < 4; ++ni)
          acc[mi][ni] = __builtin_amdgcn_mfma_f32_16x16x32_bf16(af[mi], bfr[ni], acc[mi][ni], 0, 0, 0);
    }
    __syncthreads();
  }

  if (EPI == 0) {
    unsigned short* Pout = z ? P1 : P0;
    const float* kn2 = z ? kn2b : kn2a;
    float* lsum = z ? lsum1 : lsum0;
#pragma unroll
    for (int mi = 0; mi < 4; ++mi) {
      float rs[4] = {0.f, 0.f, 0.f, 0.f};
#pragma unroll
      for (int ni = 0; ni < 4; ++ni) {
        int c = (int)n0 + wn * 64 + ni * 16 + l15;  // chunk-local col
        float kn = kn2[j0 + c];
#pragma unroll
        for (int reg = 0; reg < 4; ++reg) {
          long r = m0 + wm * 64 + mi * 16 + quad * 4 + reg;  // C-layout: row = quad*4+reg
          float v = acc[mi][ni][reg];
          float d2 = qn2[r] + kn - 2.0f * v;
          float p = __expf(SHIFT_ - INV_T * sqrtf(fmaxf(d2, 0.0f)));
          if (z && (int)r == (j0 + c)) p = 0.0f;
          rs[reg] += p;
          Pout[r * (long)pld + c] = f2bf(p);
        }
      }
#pragma unroll
      for (int reg = 0; reg < 4; ++reg) {
        float v = rs[reg];
        v += __shfl_xor(v, 1); v += __shfl_xor(v, 2);
        v += __shfl_xor(v, 4); v += __shfl_xor(v, 8);
        if (l15 == 0) atomicAdd(&lsum[m0 + wm * 64 + mi * 16 + quad * 4 + reg], v);
      }
    }
  } else {
    unsigned short* Oh = z ? O1 : O0;
#pragma unroll
    for (int mi = 0; mi < 4; ++mi)
#pragma unroll
      for (int ni = 0; ni < 4; ++ni) {
        long c = n0 + wn * 64 + ni * 16 + l15;
#pragma unroll
        for (int reg = 0; reg < 4; ++reg) {
          long r = m0 + wm * 64 + mi * 16 + quad * 4 + reg;
          long off = r * DDIM + c;
          float v = acc[mi][ni][reg];
          Oh[off] = f2bf(first ? v : (bf2f(Oh[off]) + v));
        }
      }
  }
}

// ---------------- PV GEMM, multi-chunk fused: nseg in {2,4} 16-step K-segments ----------------
// Round-10 verified pair structure extended to 4 segments. nseg is block-uniform -> guarded
// segments have uniform barriers. Unused segment pointers are never dereferenced.
#define KSEG(Abase, Bbase, LDA_, LDB_)                                                     \
  {                                                                                        \
    const unsigned short* Ab_ = (Abase) + (m0 + trow) * (LDA_) + tcol;                     \
    const unsigned short* Bb_ = (Bbase) + (n0 + trow) * (LDB_) + tcol;                     \
    for (int ks = 0; ks < 16; ++ks) {                                                      \
      const long ko = (long)ks * 64;                                                       \
      _Pragma("unroll")                                                                    \
      for (int i = 0; i < 4; ++i) gl2lds16(Ab_ + (long)i * 32 * (LDA_) + ko, Alw + i * 2048); \
      _Pragma("unroll")                                                                    \
      for (int i = 0; i < 4; ++i) gl2lds16(Bb_ + (long)i * 32 * (LDB_) + ko, Blw + i * 2048); \
      __syncthreads();                                                                     \
      _Pragma("unroll")                                                                    \
      for (int kk = 0; kk < 2; ++kk) {                                                     \
        const int uo = ue ^ (kk * 32);                                                     \
        bf16x8 af[4], bfr[4];                                                              \
        _Pragma("unroll")                                                                  \
        for (int mi = 0; mi < 4; ++mi)                                                     \
          af[mi] = *(const bf16x8*)(Al + (wm * 64 + mi * 16 + l15) * 64 + uo);             \
        _Pragma("unroll")                                                                  \
        for (int ni = 0; ni < 4; ++ni)                                                     \
          bfr[ni] = *(const bf16x8*)(Bl + (wn * 64 + ni * 16 + l15) * 64 + uo);            \
        _Pragma("unroll")                                                                  \
        for (int mi = 0; mi < 4; ++mi)                                                     \
          _Pragma("unroll")                                                                \
          for (int ni = 0; ni < 4; ++ni)                                                   \
            acc[mi][ni] = __builtin_amdgcn_mfma_f32_16x16x32_bf16(af[mi], bfr[ni], acc[mi][ni], 0, 0, 0); \
      }                                                                                    \
      __syncthreads();                                                                     \
    }                                                                                      \
  }

__launch_bounds__(256, 2)
__global__ void gemm_pv(const unsigned short* __restrict__ Pa0, const unsigned short* __restrict__ Pr0,
                        const unsigned short* __restrict__ Pa1, const unsigned short* __restrict__ Pr1,
                        const unsigned short* __restrict__ Pa2, const unsigned short* __restrict__ Pr2,
                        const unsigned short* __restrict__ Pa3, const unsigned short* __restrict__ Pr3,
                        const unsigned short* __restrict__ Va0, const unsigned short* __restrict__ Vr0,
                        const unsigned short* __restrict__ Va1, const unsigned short* __restrict__ Vr1,
                        const unsigned short* __restrict__ Va2, const unsigned short* __restrict__ Vr2,
                        const unsigned short* __restrict__ Va3, const unsigned short* __restrict__ Vr3,
                        unsigned short* __restrict__ OA, unsigned short* __restrict__ OR_,
                        int first, int nseg) {
  __shared__ __align__(16) unsigned short Al[128 * 64];
  __shared__ __align__(16) unsigned short Bl[128 * 64];

  // chunked XCD swizzle (nwg=1024, %8==0)
  const int orig = blockIdx.x + 64 * (blockIdx.y + 8 * blockIdx.z);
  const int wid = (orig & 7) * 128 + (orig >> 3);
  const int by = wid & 7;
  const int bx = (wid >> 3) & 63;
  const int z = wid >> 9;

  const unsigned short* A0 = z ? Pr0 : Pa0;
  const unsigned short* B0 = z ? Vr0 : Va0;
  const unsigned short* A1 = z ? Pr1 : Pa1;
  const unsigned short* B1 = z ? Vr1 : Va1;
  const unsigned short* A2 = z ? Pr2 : Pa2;
  const unsigned short* B2 = z ? Vr2 : Va2;
  const unsigned short* A3 = z ? Pr3 : Pa3;
  const unsigned short* B3 = z ? Vr3 : Va3;

  const int t = threadIdx.x;
  const int w = t >> 6, lane = t & 63, l15 = lane & 15, quad = lane >> 4;
  const int wm = w >> 1, wn = w & 1;
  const long m0 = (long)bx * 128;
  const long n0 = (long)by * 128;
  const int trow = t >> 3;
  const int tcol = (((t & 7) ^ (trow & 7)) * 8);

  f32x4 acc[4][4];
#pragma unroll
  for (int i = 0; i < 4; ++i)
#pragma unroll
    for (int j = 0; j < 4; ++j) acc[i][j] = (f32x4){0.f, 0.f, 0.f, 0.f};

  unsigned short* Alw = Al + t * 8;
  unsigned short* Blw = Bl + t * 8;
  const int ue = (quad ^ (l15 & 7)) * 8;

  KSEG(A0, B0, CHUNK, MROWS);
  KSEG(A1, B1, CHUNK, MROWS);
  if (nseg > 2) {
    KSEG(A2, B2, CHUNK, MROWS);
    KSEG(A3, B3, CHUNK, MROWS);
  }

  unsigned short* Oh = z ? OR_ : OA;
#pragma unroll
  for (int mi = 0; mi < 4; ++mi)
#pragma unroll
    for (int ni = 0; ni < 4; ++ni) {
      long c = n0 + wn * 64 + ni * 16 + l15;
#pragma unroll
      for (int reg = 0; reg < 4; ++reg) {
        long r = m0 + wm * 64 + mi * 16 + quad * 4 + reg;
        long off = r * DDIM + c;
        float v = acc[mi][ni][reg];
        Oh[off] = f2bf(first ? v : (bf2f(Oh[off]) + v));
      }
    }
}
#undef KSEG

// ---------------- merged epilogue: all four stats in one pass; 4 atomics/block ----------------
__global__ void epi_kernel(const unsigned short* __restrict__ OA, const unsigned short* __restrict__ OR_,
                           const float* __restrict__ lsumA, const float* __restrict__ lsumR,
                           const float* __restrict__ genf, float* __restrict__ gs) {
  __shared__ float wsL[4], wsD[4], wsA[4], wsR[4];
  const int t = threadIdx.x;
  const int w = t >> 6;
  const int lane = t & 63;
  float accL = 0.f, accD = 0.f, accA = 0.f, accR = 0.f;

  for (int i = 0; i < 8; ++i) {
    const int row = blockIdx.x * 32 + w * 8 + i;
    const float invlA = 1.0f / lsumA[row];
    const float invlR = 1.0f / lsumR[row];
    float ssA = 0.f, ssR = 0.f, ssD = 0.f;
#pragma unroll
    for (int u = 0; u < 4; ++u) {
      const long off = (long)row * DDIM + u * 256 + lane * 4;
      float4 g = *(const float4*)(genf + off);
      ushort4 oa = *(const ushort4*)(OA + off);
      ushort4 orr = *(const ushort4*)(OR_ + off);
      float g4[4] = {g.x, g.y, g.z, g.w};
      float a4[4] = {bf2f(oa.x), bf2f(oa.y), bf2f(oa.z), bf2f(oa.w)};
      float r4[4] = {bf2f(orr.x), bf2f(orr.y), bf2f(orr.z), bf2f(orr.w)};
#pragma unroll
      for (int e = 0; e < 4; ++e) {
        float a_ = a4[e] * invlA - g4[e];
        float r_ = r4[e] * invlR - g4[e];
        float d_ = a_ - r_;
        ssA += a_ * a_; ssR += r_ * r_; ssD += d_ * d_;
      }
    }
#pragma unroll
    for (int m = 1; m < 64; m <<= 1) {
      ssA += __shfl_xor(ssA, m);
      ssR += __shfl_xor(ssR, m);
      ssD += __shfl_xor(ssD, m);
    }
    accA += sqrtf(ssA); accR += sqrtf(ssR); accD += sqrtf(ssD); accL += ssD;
  }
  if (lane == 0) { wsL[w] = accL; wsD[w] = accD; wsA[w] = accA; wsR[w] = accR; }
  __syncthreads();
  if (t == 0) {
    atomicAdd(&gs[0], wsL[0] + wsL[1] + wsL[2] + wsL[3]);
    atomicAdd(&gs[1], wsD[0] + wsD[1] + wsD[2] + wsD[3]);
    atomicAdd(&gs[2], wsA[0] + wsA[1] + wsA[2] + wsA[3]);
    atomicAdd(&gs[3], wsR[0] + wsR[1] + wsR[2] + wsR[3]);
  }
}

__global__ void finalize_kernel(const float* __restrict__ gs, float* __restrict__ out) {
  int t = threadIdx.x;
  if (t == 0) out[0] = gs[0] / (8192.0f * 1024.0f);
  if (t == 1) out[1] = gs[1] / 8192.0f;
  if (t == 2) out[2] = gs[2] / 8192.0f;
  if (t == 3) out[3] = gs[3] / 8192.0f;
}

extern "C" void kernel_launch(void* const* d_in, const int* in_sizes, int n_in,
                              void* d_out, int out_size, void* d_ws, size_t ws_size,
                              hipStream_t stream) {
  const float* gen = (const float*)d_in[0];
  const float* pos = (const float*)d_in[1];
  char* ws = (char*)d_ws;
  const size_t MB = (size_t)1 << 20;
  const size_t need_quad = 224 * MB + 4 * 32768 + 64;

  unsigned short* gen_h = (unsigned short*)(ws + 0 * MB);    // 16 MB
  unsigned short* pos_h = (unsigned short*)(ws + 16 * MB);   // 16 MB
  unsigned short* genT  = (unsigned short*)(ws + 32 * MB);   // 16 MB
  unsigned short* posT  = (unsigned short*)(ws + 48 * MB);   // 16 MB

  if (ws_size >= need_quad) {
    // -------- quad path: 4 P-chunk pairs live, 2 deep PV dispatches --------
    unsigned short* Pa[4] = {(unsigned short*)(ws + 64 * MB),  (unsigned short*)(ws + 96 * MB),
                             (unsigned short*)(ws + 128 * MB), (unsigned short*)(ws + 160 * MB)};
    unsigned short* Pr[4] = {(unsigned short*)(ws + 80 * MB),  (unsigned short*)(ws + 112 * MB),
                             (unsigned short*)(ws + 144 * MB), (unsigned short*)(ws + 176 * MB)};
    unsigned short* OhA   = (unsigned short*)(ws + 192 * MB);
    unsigned short* OhR   = (unsigned short*)(ws + 208 * MB);
    float* gn2   = (float*)(ws + 224 * MB);
    float* pn2   = (float*)(ws + 224 * MB + 32768);
    float* lsumA = (float*)(ws + 224 * MB + 65536);
    float* lsumR = (float*)(ws + 224 * MB + 98304);
    float* gs    = (float*)(ws + 224 * MB + 131072);

    hipMemsetAsync(gs, 0, 4 * sizeof(float), stream);
    hipMemsetAsync(lsumA, 0, 2 * MROWS * sizeof(float), stream);
    prep_kernel<<<dim3(16384), dim3(256), 0, stream>>>(gen, pos, gen_h, pos_h, gn2, pn2);
    transpose_kernel<<<dim3(4096), dim3(256), 0, stream>>>(gen, pos, genT, posT);

    for (int p = 0; p < 2; ++p) {
      for (int q = 0; q < 4; ++q) {
        const int j0 = (4 * p + q) * CHUNK;
        gemm_bt<0><<<dim3(64, 8, 2), dim3(256), 0, stream>>>(
            gen_h, gen_h, DDIM,
            pos_h + (long)j0 * DDIM, gen_h + (long)j0 * DDIM, DDIM, DDIM / 64,
            Pa[q], Pr[q], CHUNK, j0, gn2, pn2, gn2, lsumA, lsumR, nullptr, nullptr, 0);
      }
      const long j0 = (long)(4 * p) * CHUNK;
      gemm_pv<<<dim3(64, 8, 2), dim3(256), 0, stream>>>(
          Pa[0], Pr[0], Pa[1], Pr[1], Pa[2], Pr[2], Pa[3], Pr[3],
          posT + j0, genT + j0, posT + j0 + CHUNK, genT + j0 + CHUNK,
          posT + j0 + 2 * CHUNK, genT + j0 + 2 * CHUNK, posT + j0 + 3 * CHUNK, genT + j0 + 3 * CHUNK,
          OhA, OhR, p == 0, 4);
    }

    epi_kernel<<<dim3(256), dim3(256), 0, stream>>>(OhA, OhR, lsumA, lsumR, gen, gs);
    finalize_kernel<<<dim3(1), dim3(64), 0, stream>>>(gs, (float*)d_out);
  } else {
    // -------- pair path (proven 160 MB layout): 4 PV dispatches, nseg=2 --------
    unsigned short* Pa0   = (unsigned short*)(ws + 64 * MB);
    unsigned short* Pr0   = (unsigned short*)(ws + 80 * MB);
    unsigned short* Pa1   = (unsigned short*)(ws + 96 * MB);
    unsigned short* Pr1   = (unsigned short*)(ws + 112 * MB);
    unsigned short* OhA   = (unsigned short*)(ws + 128 * MB);
    unsigned short* OhR   = (unsigned short*)(ws + 144 * MB);
    float* gn2   = (float*)(ws + 160 * MB);
    float* pn2   = (float*)(ws + 160 * MB + 32768);
    float* lsumA = (float*)(ws + 160 * MB + 65536);
    float* lsumR = (float*)(ws + 160 * MB + 98304);
    float* gs    = (float*)(ws + 160 * MB + 131072);

    hipMemsetAsync(gs, 0, 4 * sizeof(float), stream);
    hipMemsetAsync(lsumA, 0, 2 * MROWS * sizeof(float), stream);
    prep_kernel<<<dim3(16384), dim3(256), 0, stream>>>(gen, pos, gen_h, pos_h, gn2, pn2);
    transpose_kernel<<<dim3(4096), dim3(256), 0, stream>>>(gen, pos, genT, posT);

    for (int p = 0; p < 4; ++p) {
      const int j00 = (2 * p) * CHUNK, j01 = (2 * p + 1) * CHUNK;
      gemm_bt<0><<<dim3(64, 8, 2), dim3(256), 0, stream>>>(
          gen_h, gen_h, DDIM,
          pos_h + (long)j00 * DDIM, gen_h + (long)j00 * DDIM, DDIM, DDIM / 64,
          Pa0, Pr0, CHUNK, j00, gn2, pn2, gn2, lsumA, lsumR, nullptr, nullptr, 0);
      gemm_bt<0><<<dim3(64, 8, 2), dim3(256), 0, stream>>>(
          gen_h, gen_h, DDIM,
          pos_h + (long)j01 * DDIM, gen_h + (long)j01 * DDIM, DDIM, DDIM / 64,
          Pa1, Pr1, CHUNK, j01, gn2, pn2, gn2, lsumA, lsumR, nullptr, nullptr, 0);
      gemm_pv<<<dim3(64, 8, 2), dim3(256), 0, stream>>>(
          Pa0, Pr0, Pa1, Pr1, Pa0, Pr0, Pa1, Pr1,
          posT + (long)j00, genT + (long)j00, posT + (long)j01, genT + (long)j01,
          posT + (long)j00, genT + (long)j00, posT + (long)j01, genT + (long)j01,
          OhA, OhR, p == 0, 2);
    }

    epi_kernel<<<dim3(256), dim3(256), 0, stream>>>(OhA, OhR, lsumA, lsumR, gen, gs);
    finalize_kernel<<<dim3(1), dim3(64), 0, stream>>>(gs, (float*)d_out);
  }
}